// Round 1
// baseline (16846.120 us; speedup 1.0000x reference)
//
#include <hip/hip_runtime.h>
#include <math.h>
#include <stdint.h>

#define NANCH 76725
#define NPAD  131072

struct AnchorWH { float w[9]; float h[9]; };

// ---------------- conv3x3: in [256][H][W], w [Co][256][3][3], b [Co] -> out [Co][H][W]
// block 256 threads: 64 output channels x 8x8 pixel tile; each thread: 1 co, 2 rows x 8 cols
__global__ __launch_bounds__(256) void conv3x3_k(
    const float* __restrict__ in, const float* __restrict__ wgt,
    const float* __restrict__ bias, float* __restrict__ out,
    int Co, int H, int W, int relu, int tilesX)
{
    __shared__ float in_s[8][10][10];
    __shared__ float w_s[64][73];   // stride 73 (odd) -> conflict-free weight reads
    const int HW = H * W;
    const int tile = blockIdx.x;
    const int ty = tile / tilesX, tx = tile - ty * tilesX;
    const int y0 = ty * 8, x0 = tx * 8;
    const int coT = blockIdx.y * 64;
    const int tid = threadIdx.x;
    const int co_l = tid & 63;
    const int r0 = (tid >> 6) * 2;
    const int co = coT + co_l;
    const bool co_ok = co < Co;

    float acc[16];
#pragma unroll
    for (int i = 0; i < 16; i++) acc[i] = 0.f;

    for (int ci0 = 0; ci0 < 256; ci0 += 8) {
        // stage input patch 8ci x 10 x 10 (zero-padded)
        for (int idx = tid; idx < 800; idx += 256) {
            int ci = idx / 100; int rem = idx - ci * 100;
            int iy = rem / 10, ix = rem - iy * 10;
            int gy = y0 - 1 + iy, gx = x0 - 1 + ix;
            float v = 0.f;
            if (gy >= 0 && gy < H && gx >= 0 && gx < W)
                v = in[(ci0 + ci) * HW + gy * W + gx];
            in_s[ci][iy][ix] = v;
        }
        // stage weights 64co x (8ci*9)
        for (int idx = tid; idx < 64 * 72; idx += 256) {
            int row = idx / 72; int col = idx - row * 72;
            int c2 = coT + row;
            float v = 0.f;
            if (c2 < Co) v = wgt[(c2 * 256 + ci0 + col / 9) * 9 + (col % 9)];
            w_s[row][col] = v;
        }
        __syncthreads();
#pragma unroll 2
        for (int ci = 0; ci < 8; ci++) {
            float rows[4][10];
#pragma unroll
            for (int rr = 0; rr < 4; rr++)
#pragma unroll
                for (int cc = 0; cc < 10; cc++)
                    rows[rr][cc] = in_s[ci][r0 + rr][cc];  // wave-broadcast reads
#pragma unroll
            for (int ky = 0; ky < 3; ky++)
#pragma unroll
                for (int kx = 0; kx < 3; kx++) {
                    float wv = w_s[co_l][ci * 9 + ky * 3 + kx];
#pragma unroll
                    for (int r = 0; r < 2; r++)
#pragma unroll
                        for (int c = 0; c < 8; c++)
                            acc[r * 8 + c] = fmaf(wv, rows[r + ky][c + kx], acc[r * 8 + c]);
                }
        }
        __syncthreads();
    }

    if (co_ok) {
        float bv = bias[co];
#pragma unroll
        for (int r = 0; r < 2; r++) {
            int y = y0 + r0 + r;
            if (y < H) {
#pragma unroll
                for (int c = 0; c < 8; c++) {
                    int x = x0 + c;
                    if (x < W) {
                        float v = acc[r * 8 + c] + bv;
                        if (relu) v = fmaxf(v, 0.f);
                        out[co * HW + y * W + x] = v;
                    }
                }
            }
        }
    }
}

// ---------------- cls reduce: headout [720][HW] -> per-anchor (key, class)
// channel = a*80 + c ; anchor local = (y*W+x)*9 + a
__global__ void cls_reduce_k(const float* __restrict__ ho, int H, int W, int off,
                             unsigned long long* __restrict__ keys, int* __restrict__ cls_all)
{
    const int HW = H * W;
    const int n = HW * 9;
    int i = blockIdx.x * blockDim.x + threadIdx.x;
    if (i >= n) return;
    int p = i / 9, a = i - p * 9;
    const float* base = ho + (size_t)a * 80 * HW + p;
    float m = -1.f; int arg = 0;
    for (int c = 0; c < 80; c++) {
        float logit = base[(size_t)c * HW];
        float s = 1.0f / (1.0f + expf(-logit));   // fp32 sigmoid: saturates to 1.0f like reference
        if (s > m) { m = s; arg = c; }            // strict > : ties keep lowest class (jnp.argmax)
    }
    float masked = (m > 0.05f) ? m : -1.0f;
    unsigned u = __float_as_uint(masked);
    unsigned s = (u & 0x80000000u) ? ~u : (u | 0x80000000u);  // order-preserving float->uint
    int g = off + i;
    keys[g] = ((unsigned long long)s << 32) | (unsigned long long)(0xFFFFFFFFu - (unsigned)g);
    cls_all[g] = arg;
}

// ---------------- reg decode: regout [36][HW] -> boxes_all [anchor][4] (clipped)
__global__ void decode_k(const float* __restrict__ ro, int H, int W, int off,
                         float strd, AnchorWH awh, float* __restrict__ boxes_all)
{
    const int HW = H * W;
    const int n = HW * 9;
    int i = blockIdx.x * blockDim.x + threadIdx.x;
    if (i >= n) return;
    int p = i / 9, a = i - p * 9;
    int y = p / W, x = p - y * W;
    float cx0 = ((float)x + 0.5f) * strd;
    float cy0 = ((float)y + 0.5f) * strd;
    // anchor corners (then re-derive w/h/cx/cy like the reference decode does)
    float ax1 = cx0 - awh.w[a] / 2.0f;
    float ax2 = cx0 + awh.w[a] / 2.0f;
    float ay1 = cy0 - awh.h[a] / 2.0f;
    float ay2 = cy0 + awh.h[a] / 2.0f;
    float w = ax2 - ax1, h = ay2 - ay1;
    float cx = ax1 + 0.5f * w, cy = ay1 + 0.5f * h;
    float l0 = ro[(size_t)(a * 4 + 0) * HW + p];
    float l1 = ro[(size_t)(a * 4 + 1) * HW + p];
    float l2 = ro[(size_t)(a * 4 + 2) * HW + p];
    float l3 = ro[(size_t)(a * 4 + 3) * HW + p];
    float dx = l0 * 0.1f, dy = l1 * 0.1f, dw = l2 * 0.2f, dh = l3 * 0.2f;
    float pcx = cx + dx * w, pcy = cy + dy * h;
    float pw = expf(dw) * w, ph = expf(dh) * h;
    float bx1 = pcx - 0.5f * pw, by1 = pcy - 0.5f * ph;
    float bx2 = pcx + 0.5f * pw, by2 = pcy + 0.5f * ph;
    bx1 = fminf(fmaxf(bx1, 0.f), 640.f);
    by1 = fminf(fmaxf(by1, 0.f), 640.f);
    bx2 = fminf(fmaxf(bx2, 0.f), 640.f);
    by2 = fminf(fmaxf(by2, 0.f), 640.f);
    int g = off + i;
    boxes_all[g * 4 + 0] = bx1;
    boxes_all[g * 4 + 1] = by1;
    boxes_all[g * 4 + 2] = bx2;
    boxes_all[g * 4 + 3] = by2;
}

__global__ void pad_keys_k(unsigned long long* __restrict__ keys)
{
    int i = blockIdx.x * blockDim.x + threadIdx.x + NANCH;
    if (i < NPAD) keys[i] = 0ULL;
}

// ---------------- bitonic sort (descending) over NPAD u64 keys
__global__ void bitonic_global_k(unsigned long long* __restrict__ keys, int size, int stride)
{
    int t = blockIdx.x * blockDim.x + threadIdx.x;  // NPAD/2 threads
    int low = t & (stride - 1);
    int i = ((t - low) << 1) | low;
    int j = i + stride;
    bool desc = ((i & size) == 0);
    unsigned long long a = keys[i], b = keys[j];
    if (desc ? (a < b) : (a > b)) { keys[i] = b; keys[j] = a; }
}

__global__ __launch_bounds__(1024) void bitonic_local_full_k(unsigned long long* __restrict__ keys)
{
    __shared__ unsigned long long s[4096];
    const int base = blockIdx.x * 4096;
    for (int i = threadIdx.x; i < 4096; i += 1024) s[i] = keys[base + i];
    __syncthreads();
    for (int size = 2; size <= 4096; size <<= 1) {
        for (int stride = size >> 1; stride > 0; stride >>= 1) {
            for (int t = threadIdx.x; t < 2048; t += 1024) {
                int low = t & (stride - 1);
                int i = ((t - low) << 1) | low;
                int j = i + stride;
                bool desc = (((base + i) & size) == 0);
                unsigned long long a = s[i], b = s[j];
                if (desc ? (a < b) : (a > b)) { s[i] = b; s[j] = a; }
            }
            __syncthreads();
        }
    }
    for (int i = threadIdx.x; i < 4096; i += 1024) keys[base + i] = s[i];
}

__global__ __launch_bounds__(1024) void bitonic_local_k(unsigned long long* __restrict__ keys, int size)
{
    __shared__ unsigned long long s[4096];
    const int base = blockIdx.x * 4096;
    for (int i = threadIdx.x; i < 4096; i += 1024) s[i] = keys[base + i];
    __syncthreads();
    const bool desc = ((base & size) == 0);   // size >= 8192: direction uniform per chunk
    for (int stride = 2048; stride > 0; stride >>= 1) {
        for (int t = threadIdx.x; t < 2048; t += 1024) {
            int low = t & (stride - 1);
            int i = ((t - low) << 1) | low;
            int j = i + stride;
            unsigned long long a = s[i], b = s[j];
            if (desc ? (a < b) : (a > b)) { s[i] = b; s[j] = a; }
        }
        __syncthreads();
    }
    for (int i = threadIdx.x; i < 4096; i += 1024) keys[base + i] = s[i];
}

// ---------------- NMS + outputs (single block, 1024 threads)
__global__ __launch_bounds__(1024) void nms_out_k(
    const unsigned long long* __restrict__ keys,
    const float* __restrict__ boxes_all,
    const int* __restrict__ cls_all,
    float* __restrict__ out)
{
    __shared__ float X1[1000], Y1[1000], X2[1000], Y2[1000], AR[1000], SV[1000];
    __shared__ int KP[1000], AN[1000];
    __shared__ int curI;
    const int tid = threadIdx.x;
    for (int i = tid; i < 1000; i += 1024) {
        unsigned long long k = keys[i];
        unsigned shi = (unsigned)(k >> 32);
        unsigned u = (shi & 0x80000000u) ? (shi ^ 0x80000000u) : ~shi;
        float val = __uint_as_float(u);
        int anchor = (int)(0xFFFFFFFFu - (unsigned)(k & 0xFFFFFFFFull));
        float x1 = boxes_all[anchor * 4 + 0];
        float y1 = boxes_all[anchor * 4 + 1];
        float x2 = boxes_all[anchor * 4 + 2];
        float y2 = boxes_all[anchor * 4 + 3];
        X1[i] = x1; Y1[i] = y1; X2[i] = x2; Y2[i] = y2;
        AR[i] = fmaxf(x2 - x1, 0.f) * fmaxf(y2 - y1, 0.f);
        SV[i] = val; AN[i] = anchor;
        KP[i] = (val > 0.0f) ? 1 : 0;
    }
    if (tid == 0) curI = 0;
    __syncthreads();
    while (true) {
        if (tid == 0) {
            int j = curI;
            while (j < 1000 && !KP[j]) j++;
            curI = j;
        }
        __syncthreads();
        int i = curI;
        if (i >= 1000) break;
        float x1 = X1[i], y1 = Y1[i], x2 = X2[i], y2 = Y2[i], ar = AR[i];
        for (int j = i + 1 + tid; j < 1000; j += 1024) {
            if (KP[j]) {
                float xx1 = fmaxf(x1, X1[j]), yy1 = fmaxf(y1, Y1[j]);
                float xx2 = fminf(x2, X2[j]), yy2 = fminf(y2, Y2[j]);
                float inter = fmaxf(xx2 - xx1, 0.f) * fmaxf(yy2 - yy1, 0.f);
                float iou = inter / (ar + AR[j] - inter + 1e-8f);
                if (iou > 0.5f) KP[j] = 0;
            }
        }
        if (tid == 0) curI = i + 1;
        __syncthreads();
    }
    // outputs: [scores(1000) | classes(1000) | boxes(4000) | keep(1000)]
    for (int i = tid; i < 1000; i += 1024) {
        float m = KP[i] ? 1.f : 0.f;
        out[i] = KP[i] ? SV[i] : 0.f;
        out[1000 + i] = (float)cls_all[AN[i]];
        out[2000 + i * 4 + 0] = m * X1[i];
        out[2000 + i * 4 + 1] = m * Y1[i];
        out[2000 + i * 4 + 2] = m * X2[i];
        out[2000 + i * 4 + 3] = m * Y2[i];
        out[6000 + i] = m;
    }
}

extern "C" void kernel_launch(void* const* d_in, const int* in_sizes, int n_in,
                              void* d_out, int out_size, void* d_ws, size_t ws_size,
                              hipStream_t stream)
{
    const float* feats[5];
    for (int i = 0; i < 5; i++) feats[i] = (const float*)d_in[i];
    const float* cls_w  = (const float*)d_in[5];
    const float* cls_b  = (const float*)d_in[6];
    const float* cls_hw = (const float*)d_in[7];
    const float* cls_hb = (const float*)d_in[8];
    const float* reg_w  = (const float*)d_in[9];
    const float* reg_b  = (const float*)d_in[10];
    const float* reg_hw = (const float*)d_in[11];
    const float* reg_hb = (const float*)d_in[12];
    float* out = (float*)d_out;

    // workspace layout (~34.2 MB)
    char* ws = (char*)d_ws;
    unsigned long long* keys = (unsigned long long*)ws; ws += (size_t)NPAD * 8;
    float* actA    = (float*)ws; ws += (size_t)256 * 6400 * 4;
    float* actB    = (float*)ws; ws += (size_t)256 * 6400 * 4;
    float* headout = (float*)ws; ws += (size_t)720 * 6400 * 4;
    int*   cls_all = (int*)ws;   ws += (size_t)NANCH * 4;
    float* boxes_all = (float*)ws; ws += (size_t)NANCH * 4 * 4;

    const int   Hs[5]   = {80, 40, 20, 10, 5};
    const float strd[5] = {8.f, 16.f, 32.f, 64.f, 128.f};
    const float sz[5]   = {32.f, 64.f, 128.f, 256.f, 512.f};
    const int   offs[5] = {0, 57600, 72000, 75600, 76500};
    const float ratios[3] = {0.5f, 1.0f, 2.0f};
    const float scales[3] = {1.0f, 1.25992104989487316477f, 1.58740105196819947475f};

    pad_keys_k<<<(NPAD - NANCH + 255) / 256, 256, 0, stream>>>(keys);

    for (int lv = 0; lv < 5; lv++) {
        const int H = Hs[lv], W = H, HW = H * W;
        const int tilesX = (W + 7) / 8;
        const int nt = tilesX * tilesX;
        const int na = HW * 9;

        // ---- classification head
        conv3x3_k<<<dim3(nt, 4), 256, 0, stream>>>(feats[lv], cls_w + 0 * 589824, cls_b + 0, actA, 256, H, W, 1, tilesX);
        conv3x3_k<<<dim3(nt, 4), 256, 0, stream>>>(actA, cls_w + 1 * 589824, cls_b + 256, actB, 256, H, W, 1, tilesX);
        conv3x3_k<<<dim3(nt, 4), 256, 0, stream>>>(actB, cls_w + 2 * 589824, cls_b + 512, actA, 256, H, W, 1, tilesX);
        conv3x3_k<<<dim3(nt, 4), 256, 0, stream>>>(actA, cls_w + 3 * 589824, cls_b + 768, actB, 256, H, W, 1, tilesX);
        conv3x3_k<<<dim3(nt, 12), 256, 0, stream>>>(actB, cls_hw, cls_hb, headout, 720, H, W, 0, tilesX);
        cls_reduce_k<<<(na + 255) / 256, 256, 0, stream>>>(headout, H, W, offs[lv], keys, cls_all);

        // ---- regression head
        conv3x3_k<<<dim3(nt, 4), 256, 0, stream>>>(feats[lv], reg_w + 0 * 589824, reg_b + 0, actA, 256, H, W, 1, tilesX);
        conv3x3_k<<<dim3(nt, 4), 256, 0, stream>>>(actA, reg_w + 1 * 589824, reg_b + 256, actB, 256, H, W, 1, tilesX);
        conv3x3_k<<<dim3(nt, 4), 256, 0, stream>>>(actB, reg_w + 2 * 589824, reg_b + 512, actA, 256, H, W, 1, tilesX);
        conv3x3_k<<<dim3(nt, 4), 256, 0, stream>>>(actA, reg_w + 3 * 589824, reg_b + 768, actB, 256, H, W, 1, tilesX);
        conv3x3_k<<<dim3(nt, 1), 256, 0, stream>>>(actB, reg_hw, reg_hb, headout, 36, H, W, 0, tilesX);

        AnchorWH awh;
        for (int r = 0; r < 3; r++)
            for (int s = 0; s < 3; s++) {
                awh.w[r * 3 + s] = sz[lv] * scales[s] / sqrtf(ratios[r]);
                awh.h[r * 3 + s] = sz[lv] * scales[s] * sqrtf(ratios[r]);
            }
        decode_k<<<(na + 255) / 256, 256, 0, stream>>>(headout, H, W, offs[lv], strd[lv], awh, boxes_all);
    }

    // ---- descending bitonic sort of keys
    bitonic_local_full_k<<<NPAD / 4096, 1024, 0, stream>>>(keys);
    for (int size = 8192; size <= NPAD; size <<= 1) {
        for (int stride = size >> 1; stride >= 4096; stride >>= 1)
            bitonic_global_k<<<NPAD / 2 / 1024, 1024, 0, stream>>>(keys, size, stride);
        bitonic_local_k<<<NPAD / 4096, 1024, 0, stream>>>(keys, size);
    }

    // ---- NMS + write outputs
    nms_out_k<<<1, 1024, 0, stream>>>(keys, boxes_all, cls_all, out);
}

// Round 3
// 1798.102 us; speedup vs baseline: 9.3688x; 9.3688x over previous
//
#include <hip/hip_runtime.h>
#include <math.h>
#include <stdint.h>

#define NANCH 76725
#define NPAD  131072
#define PXTOT 8525

typedef _Float16 half8 __attribute__((ext_vector_type(8)));
typedef float float4v __attribute__((ext_vector_type(4)));

// activation / head buffer element sizes (floats)
#define ACT_EL   (256 * PXTOT)                 // 2,182,400
#define HEADC_EL (720 * PXTOT)                 // 6,138,000
#define HEADR_EL (36 * PXTOT)                  //   306,900

// prepped weight sizes (fp16 elements): [tap9][split2][CoPad][256]
#define TRUNK_WP_EL (9 * 2 * 256 * 256)
#define CLSH_WP_EL  (9 * 2 * 768 * 256)
#define REGH_WP_EL  (9 * 2 * 64 * 256)

// ---------------------------------------------------------------- weight prep
// src: [Co][256][3][3] fp32   ->   dst: [tap][split][CoPad][ci 256] fp16
struct PrepArgs {
    const float* src[10];
    _Float16*    dst[10];
    int Co[10], CoPad[10];
    long base[11];   // cumulative thread base, threads per entry = 18*Co*32
};

__global__ __launch_bounds__(256) void prep_k(PrepArgs P)
{
    long idx = (long)blockIdx.x * 256 + threadIdx.x;
    if (idx >= P.base[10]) return;
    int e = 0;
    while (idx >= P.base[e + 1]) e++;
    long local = idx - P.base[e];
    int k = (int)(local & 31);           // ci group (8 ci each)
    long t2 = local >> 5;                // (tap,s,co)
    int Co = P.Co[e];
    int co = (int)(t2 % Co);
    int ts = (int)(t2 / Co);             // 0..17
    int tap = ts >> 1, s = ts & 1;
    int ci0 = k * 8;
    const float* src = P.src[e];
    half8 out;
#pragma unroll
    for (int j = 0; j < 8; j++) {
        float v = src[(size_t)(co * 256 + ci0 + j) * 9 + tap];
        _Float16 h = (_Float16)v;
        out[j] = s ? (_Float16)(v - (float)h) : h;
    }
    _Float16* dst = P.dst[e] + ((size_t)(tap * 2 + s) * P.CoPad[e] + co) * 256 + ci0;
    *(half8*)dst = out;
}

// ---------------------------------------------------------------- MFMA conv
// GEMM: C[px][co] = sum_{tap,ci} X[px + shift(tap)][ci] * W[tap][ci][co]
// block: 64 px  x 256 co; 4 waves, wave w -> co [64w, 64w+64)
// A (activations) fp16 hi/lo staged in LDS; B (weights) direct global (prepped)
struct ConvArgs {
    const float* src0[5];
    const float* src1[5];
    float* dst0; float* dst1;
    const _Float16* wp0; const _Float16* wp1;
    const float* bias0; const float* bias1;
    int Co0, Co1, CoPad0, CoPad1, relu, chunks0, chunks1;
};

__global__ __launch_bounds__(256, 3) void conv_mfma_k(ConvArgs A)
{
    __shared__ __align__(16) _Float16 Xs[228 * 72];

    const int cumT[5] = {100, 125, 132, 134, 135};
    const int Wt[5]   = {80, 40, 20, 10, 5};
    const int pxB[5]  = {0, 6400, 8000, 8400, 8500};

    const int gid = blockIdx.x;
    int head, chunk, t;
    if (gid < 135 * A.chunks0) { head = 0; chunk = gid / 135; t = gid % 135; }
    else { int g = gid - 135 * A.chunks0; head = 1; chunk = g / 135; t = g % 135; }

    int lv = 0;
    while (t >= cumT[lv]) lv++;
    const int tile = t - (lv ? cumT[lv - 1] : 0);
    const int W = Wt[lv], HW = W * W;
    const int pxStart = tile * 64;
    const int Ns = 2 * W + 67;

    const float* src = head ? A.src1[lv] : A.src0[lv];
    float* dst       = head ? A.dst1 : A.dst0;
    const _Float16* wp = head ? A.wp1 : A.wp0;
    const float* bias  = head ? A.bias1 : A.bias0;
    const int Co     = head ? A.Co1 : A.Co0;
    const int CoPad  = head ? A.CoPad1 : A.CoPad0;
    dst += (size_t)Co * pxB[lv];

    const int tid = threadIdx.x;
    const int lane = tid & 63;
    const int wv = tid >> 6;
    const int l15 = lane & 15;
    const int quad = lane >> 4;
    const int coW = chunk * 256 + wv * 64;

    float4v acc[4][4];
#pragma unroll
    for (int i = 0; i < 4; i++)
#pragma unroll
        for (int j = 0; j < 4; j++) acc[i][j] = (float4v){0.f, 0.f, 0.f, 0.f};

    int xA[4];
#pragma unroll
    for (int mf = 0; mf < 4; mf++) {
        int px = pxStart + mf * 16 + l15;
        xA[mf] = px % W;
    }
    const half8 z8 = {(_Float16)0, (_Float16)0, (_Float16)0, (_Float16)0,
                      (_Float16)0, (_Float16)0, (_Float16)0, (_Float16)0};

    for (int ci0 = 0; ci0 < 256; ci0 += 32) {
        __syncthreads();
        {   // stage input patch (hi/lo) for this ci chunk
            const int p0 = pxStart - W - 1;
            for (int ci = wv; ci < 32; ci += 4) {
                const float* s = src + (size_t)(ci0 + ci) * HW;
                for (int sp = lane; sp < Ns; sp += 64) {
                    int p = p0 + sp;
                    float v = (p >= 0 && p < HW) ? s[p] : 0.f;
                    _Float16 h = (_Float16)v;
                    Xs[sp * 72 + ci] = h;
                    Xs[sp * 72 + 32 + ci] = (_Float16)(v - (float)h);
                }
            }
        }
        __syncthreads();

        for (int tap = 0; tap < 9; tap++) {
            const int dy = tap / 3 - 1, dx = tap % 3 - 1;
            half8 ah[4], al[4];
#pragma unroll
            for (int mf = 0; mf < 4; mf++) {
                int xx = xA[mf] + dx;
                bool val = (xx >= 0) && (xx < W);
                int row = (mf * 16 + l15) + (W + 1) + dy * W + dx;
                const _Float16* ap = &Xs[row * 72 + quad * 8];
                ah[mf] = val ? *(const half8*)ap : z8;
                al[mf] = val ? *(const half8*)(ap + 32) : z8;
            }
            const _Float16* wpt  = wp + (size_t)(tap * 2) * CoPad * 256 + ci0 + quad * 8;
            const _Float16* wptl = wpt + (size_t)CoPad * 256;
#pragma unroll
            for (int nf = 0; nf < 4; nf++) {
                int co = coW + nf * 16 + l15;
                bool bok = co < CoPad;
                half8 bh = bok ? *(const half8*)(wpt  + (size_t)co * 256) : z8;
                half8 bl = bok ? *(const half8*)(wptl + (size_t)co * 256) : z8;
#pragma unroll
                for (int mf = 0; mf < 4; mf++) {
                    acc[mf][nf] = __builtin_amdgcn_mfma_f32_16x16x32_f16(ah[mf], bh, acc[mf][nf], 0, 0, 0);
                    acc[mf][nf] = __builtin_amdgcn_mfma_f32_16x16x32_f16(ah[mf], bl, acc[mf][nf], 0, 0, 0);
                    acc[mf][nf] = __builtin_amdgcn_mfma_f32_16x16x32_f16(al[mf], bh, acc[mf][nf], 0, 0, 0);
                }
            }
        }
    }

    // epilogue: C row = quad*4 + r, col = l15
#pragma unroll
    for (int nf = 0; nf < 4; nf++) {
        int co = coW + nf * 16 + l15;
        if (co >= Co) continue;
        float bv = bias[co];
        float* dco = dst + (size_t)co * HW;
#pragma unroll
        for (int mf = 0; mf < 4; mf++) {
            int pbase = pxStart + mf * 16 + quad * 4;
#pragma unroll
            for (int r = 0; r < 4; r++) {
                int p = pbase + r;
                if (p < HW) {
                    float v = acc[mf][nf][r] + bv;
                    if (A.relu) v = fmaxf(v, 0.f);
                    dco[p] = v;
                }
            }
        }
    }
}

// ---------------------------------------------------------------- cls reduce
// headout_cls layout per level: base 720*pxB + (a*80+c)*HW + p
// IMPORTANT: argmax must be done in SIGMOID domain (fp32). Logits saturate
// sigmoid to exactly 1.0f; jnp.argmax over sigmoid values picks the LOWEST
// class index among saturated ties — argmax over logits picks a different one.
__global__ void cls_reduce_k(const float* __restrict__ ho,
                             unsigned long long* __restrict__ keys, int* __restrict__ cls_all)
{
    const int cumB[5] = {225, 282, 297, 301, 302};
    const int HWs[5]  = {6400, 1600, 400, 100, 25};
    const int pxB[5]  = {0, 6400, 8000, 8400, 8500};
    const int offs[5] = {0, 57600, 72000, 75600, 76500};
    int b = blockIdx.x;
    int lv = 0;
    while (b >= cumB[lv]) lv++;
    int local = (b - (lv ? cumB[lv - 1] : 0)) * 256 + threadIdx.x;
    const int HW = HWs[lv];
    if (local >= HW * 9) return;
    int a = local / HW, p = local - a * HW;
    const float* base = ho + (size_t)720 * pxB[lv] + (size_t)a * 80 * HW + p;
    float m = -1.f; int arg = 0;
    for (int c = 0; c < 80; c++) {
        float logit = base[(size_t)c * HW];
        float s = 1.0f / (1.0f + expf(-logit));   // fp32 sigmoid (saturates to 1.0f)
        if (s > m) { m = s; arg = c; }            // strict > : ties keep lowest class
    }
    float masked = (m > 0.05f) ? m : -1.0f;
    unsigned u = __float_as_uint(masked);
    unsigned su = (u & 0x80000000u) ? ~u : (u | 0x80000000u);
    int g = offs[lv] + p * 9 + a;
    keys[g] = ((unsigned long long)su << 32) | (unsigned long long)(0xFFFFFFFFu - (unsigned)g);
    cls_all[g] = arg;
}

// ---------------------------------------------------------------- decode
struct DecArgs { float aw[45]; float ah[45]; };

__global__ void decode_k(const float* __restrict__ ro, DecArgs D, float* __restrict__ boxes_all)
{
    const int cumB[5] = {225, 282, 297, 301, 302};
    const int HWs[5]  = {6400, 1600, 400, 100, 25};
    const int Wt[5]   = {80, 40, 20, 10, 5};
    const int pxB[5]  = {0, 6400, 8000, 8400, 8500};
    const int offs[5] = {0, 57600, 72000, 75600, 76500};
    const float strd[5] = {8.f, 16.f, 32.f, 64.f, 128.f};
    int b = blockIdx.x;
    int lv = 0;
    while (b >= cumB[lv]) lv++;
    int local = (b - (lv ? cumB[lv - 1] : 0)) * 256 + threadIdx.x;
    const int HW = HWs[lv], W = Wt[lv];
    if (local >= HW * 9) return;
    int a = local / HW, p = local - a * HW;
    int y = p / W, x = p - y * W;
    float cx0 = ((float)x + 0.5f) * strd[lv];
    float cy0 = ((float)y + 0.5f) * strd[lv];
    float aw = D.aw[lv * 9 + a], ahh = D.ah[lv * 9 + a];
    float ax1 = cx0 - aw * 0.5f, ax2 = cx0 + aw * 0.5f;
    float ay1 = cy0 - ahh * 0.5f, ay2 = cy0 + ahh * 0.5f;
    float w = ax2 - ax1, h = ay2 - ay1;
    float cx = ax1 + 0.5f * w, cy = ay1 + 0.5f * h;
    const float* base = ro + (size_t)36 * pxB[lv] + p;
    float l0 = base[(size_t)(a * 4 + 0) * HW];
    float l1 = base[(size_t)(a * 4 + 1) * HW];
    float l2 = base[(size_t)(a * 4 + 2) * HW];
    float l3 = base[(size_t)(a * 4 + 3) * HW];
    float dx = l0 * 0.1f, dy = l1 * 0.1f, dw = l2 * 0.2f, dh = l3 * 0.2f;
    float pcx = cx + dx * w, pcy = cy + dy * h;
    float pw = expf(dw) * w, ph = expf(dh) * h;
    float bx1 = fminf(fmaxf(pcx - 0.5f * pw, 0.f), 640.f);
    float by1 = fminf(fmaxf(pcy - 0.5f * ph, 0.f), 640.f);
    float bx2 = fminf(fmaxf(pcx + 0.5f * pw, 0.f), 640.f);
    float by2 = fminf(fmaxf(pcy + 0.5f * ph, 0.f), 640.f);
    int g = offs[lv] + p * 9 + a;
    boxes_all[g * 4 + 0] = bx1;
    boxes_all[g * 4 + 1] = by1;
    boxes_all[g * 4 + 2] = bx2;
    boxes_all[g * 4 + 3] = by2;
}

__global__ void pad_keys_k(unsigned long long* __restrict__ keys)
{
    int i = blockIdx.x * blockDim.x + threadIdx.x + NANCH;
    if (i < NPAD) keys[i] = 0ULL;
}

// ---------------------------------------------------------------- bitonic sort
__global__ void bitonic_global_k(unsigned long long* __restrict__ keys, int size, int stride)
{
    int t = blockIdx.x * blockDim.x + threadIdx.x;
    int low = t & (stride - 1);
    int i = ((t - low) << 1) | low;
    int j = i + stride;
    bool desc = ((i & size) == 0);
    unsigned long long a = keys[i], b = keys[j];
    if (desc ? (a < b) : (a > b)) { keys[i] = b; keys[j] = a; }
}

__global__ __launch_bounds__(1024) void bitonic_local_full_k(unsigned long long* __restrict__ keys)
{
    __shared__ unsigned long long s[4096];
    const int base = blockIdx.x * 4096;
    for (int i = threadIdx.x; i < 4096; i += 1024) s[i] = keys[base + i];
    __syncthreads();
    for (int size = 2; size <= 4096; size <<= 1) {
        for (int stride = size >> 1; stride > 0; stride >>= 1) {
            for (int t = threadIdx.x; t < 2048; t += 1024) {
                int low = t & (stride - 1);
                int i = ((t - low) << 1) | low;
                int j = i + stride;
                bool desc = (((base + i) & size) == 0);
                unsigned long long a = s[i], b = s[j];
                if (desc ? (a < b) : (a > b)) { s[i] = b; s[j] = a; }
            }
            __syncthreads();
        }
    }
    for (int i = threadIdx.x; i < 4096; i += 1024) keys[base + i] = s[i];
}

__global__ __launch_bounds__(1024) void bitonic_local_k(unsigned long long* __restrict__ keys, int size)
{
    __shared__ unsigned long long s[4096];
    const int base = blockIdx.x * 4096;
    for (int i = threadIdx.x; i < 4096; i += 1024) s[i] = keys[base + i];
    __syncthreads();
    const bool desc = ((base & size) == 0);
    for (int stride = 2048; stride > 0; stride >>= 1) {
        for (int t = threadIdx.x; t < 2048; t += 1024) {
            int low = t & (stride - 1);
            int i = ((t - low) << 1) | low;
            int j = i + stride;
            unsigned long long a = s[i], b = s[j];
            if (desc ? (a < b) : (a > b)) { s[i] = b; s[j] = a; }
        }
        __syncthreads();
    }
    for (int i = threadIdx.x; i < 4096; i += 1024) keys[base + i] = s[i];
}

// ---------------------------------------------------------------- NMS + out
__global__ __launch_bounds__(1024) void nms_out_k(
    const unsigned long long* __restrict__ keys,
    const float* __restrict__ boxes_all,
    const int* __restrict__ cls_all,
    float* __restrict__ out)
{
    __shared__ float X1[1000], Y1[1000], X2[1000], Y2[1000], AR[1000], SV[1000];
    __shared__ int KP[1000], AN[1000];
    __shared__ int curI;
    const int tid = threadIdx.x;
    for (int i = tid; i < 1000; i += 1024) {
        unsigned long long k = keys[i];
        unsigned shi = (unsigned)(k >> 32);
        unsigned u = (shi & 0x80000000u) ? (shi ^ 0x80000000u) : ~shi;
        float val = __uint_as_float(u);
        int anchor = (int)(0xFFFFFFFFu - (unsigned)(k & 0xFFFFFFFFull));
        float x1 = boxes_all[anchor * 4 + 0];
        float y1 = boxes_all[anchor * 4 + 1];
        float x2 = boxes_all[anchor * 4 + 2];
        float y2 = boxes_all[anchor * 4 + 3];
        X1[i] = x1; Y1[i] = y1; X2[i] = x2; Y2[i] = y2;
        AR[i] = fmaxf(x2 - x1, 0.f) * fmaxf(y2 - y1, 0.f);
        SV[i] = val; AN[i] = anchor;
        KP[i] = (val > 0.0f) ? 1 : 0;
    }
    if (tid == 0) curI = 0;
    __syncthreads();
    while (true) {
        if (tid == 0) {
            int j = curI;
            while (j < 1000 && !KP[j]) j++;
            curI = j;
        }
        __syncthreads();
        int i = curI;
        if (i >= 1000) break;
        float x1 = X1[i], y1 = Y1[i], x2 = X2[i], y2 = Y2[i], ar = AR[i];
        for (int j = i + 1 + tid; j < 1000; j += 1024) {
            if (KP[j]) {
                float xx1 = fmaxf(x1, X1[j]), yy1 = fmaxf(y1, Y1[j]);
                float xx2 = fminf(x2, X2[j]), yy2 = fminf(y2, Y2[j]);
                float inter = fmaxf(xx2 - xx1, 0.f) * fmaxf(yy2 - yy1, 0.f);
                float iou = inter / (ar + AR[j] - inter + 1e-8f);
                if (iou > 0.5f) KP[j] = 0;
            }
        }
        if (tid == 0) curI = i + 1;
        __syncthreads();
    }
    for (int i = tid; i < 1000; i += 1024) {
        float m = KP[i] ? 1.f : 0.f;
        out[i] = KP[i] ? SV[i] : 0.f;
        out[1000 + i] = (float)cls_all[AN[i]];
        out[2000 + i * 4 + 0] = m * X1[i];
        out[2000 + i * 4 + 1] = m * Y1[i];
        out[2000 + i * 4 + 2] = m * X2[i];
        out[2000 + i * 4 + 3] = m * Y2[i];
        out[6000 + i] = m;
    }
}

// ---------------------------------------------------------------- host
extern "C" void kernel_launch(void* const* d_in, const int* in_sizes, int n_in,
                              void* d_out, int out_size, void* d_ws, size_t ws_size,
                              hipStream_t stream)
{
    const float* feats[5];
    for (int i = 0; i < 5; i++) feats[i] = (const float*)d_in[i];
    const float* cls_w  = (const float*)d_in[5];
    const float* cls_b  = (const float*)d_in[6];
    const float* cls_hw = (const float*)d_in[7];
    const float* cls_hb = (const float*)d_in[8];
    const float* reg_w  = (const float*)d_in[9];
    const float* reg_b  = (const float*)d_in[10];
    const float* reg_hw = (const float*)d_in[11];
    const float* reg_hb = (const float*)d_in[12];
    float* out = (float*)d_out;

    // ---------- workspace layout
    char* ws = (char*)d_ws;
    size_t off = 0;
    auto alloc = [&](size_t sz) { size_t o = off; off += (sz + 255) & ~(size_t)255; return o; };

    size_t R0 = alloc((size_t)(HEADC_EL + HEADR_EL) * 4);   // headout region; overlays act-A buffers
    float* actA_cls = (float*)(ws + R0);
    float* actA_reg = actA_cls + ACT_EL;
    float* headout_cls = (float*)(ws + R0);
    float* headout_reg = headout_cls + HEADC_EL;

    float* actB_cls = (float*)(ws + alloc((size_t)ACT_EL * 4));
    float* actB_reg = (float*)(ws + alloc((size_t)ACT_EL * 4));

    _Float16* wpc[4]; _Float16* wpr[4];
    for (int i = 0; i < 4; i++) wpc[i] = (_Float16*)(ws + alloc((size_t)TRUNK_WP_EL * 2));
    _Float16* wpch = (_Float16*)(ws + alloc((size_t)CLSH_WP_EL * 2));
    for (int i = 0; i < 4; i++) wpr[i] = (_Float16*)(ws + alloc((size_t)TRUNK_WP_EL * 2));
    _Float16* wprh = (_Float16*)(ws + alloc((size_t)REGH_WP_EL * 2));

    unsigned long long* keys = (unsigned long long*)(ws + alloc((size_t)NPAD * 8));
    float* boxes_all = (float*)(ws + alloc((size_t)NANCH * 16));
    int* cls_all = (int*)(ws + alloc((size_t)NANCH * 4));
    (void)ws_size;

    // ---------- weight prep
    PrepArgs P;
    long cum = 0;
    for (int e = 0; e < 10; e++) {
        const float* src; _Float16* dst; int Co, CoPad;
        if (e < 4)      { src = cls_w + (size_t)e * 589824; dst = wpc[e]; Co = 256; CoPad = 256; }
        else if (e == 4){ src = cls_hw;                     dst = wpch;   Co = 720; CoPad = 768; }
        else if (e < 9) { src = reg_w + (size_t)(e - 5) * 589824; dst = wpr[e - 5]; Co = 256; CoPad = 256; }
        else            { src = reg_hw;                     dst = wprh;   Co = 36;  CoPad = 64; }
        P.src[e] = src; P.dst[e] = dst; P.Co[e] = Co; P.CoPad[e] = CoPad;
        P.base[e] = cum; cum += (long)18 * Co * 32;
    }
    P.base[10] = cum;
    prep_k<<<(int)((cum + 255) / 256), 256, 0, stream>>>(P);

    pad_keys_k<<<(NPAD - NANCH + 255) / 256, 256, 0, stream>>>(keys);

    const int pxB[5] = {0, 6400, 8000, 8400, 8500};

    // ---------- conv layers (both heads, all levels per launch)
    auto mkTrunk = [&](const float* s0base, const float* s1base, bool isFeat,
                       float* d0, float* d1, const _Float16* w0, const _Float16* w1,
                       const float* b0, const float* b1) {
        ConvArgs C;
        for (int lv = 0; lv < 5; lv++) {
            C.src0[lv] = isFeat ? feats[lv] : s0base + (size_t)256 * pxB[lv];
            C.src1[lv] = isFeat ? feats[lv] : s1base + (size_t)256 * pxB[lv];
        }
        C.dst0 = d0; C.dst1 = d1; C.wp0 = w0; C.wp1 = w1; C.bias0 = b0; C.bias1 = b1;
        C.Co0 = 256; C.Co1 = 256; C.CoPad0 = 256; C.CoPad1 = 256;
        C.relu = 1; C.chunks0 = 1; C.chunks1 = 1;
        return C;
    };

    {   // L1
        ConvArgs C = mkTrunk(nullptr, nullptr, true, actA_cls, actA_reg, wpc[0], wpr[0],
                             cls_b + 0, reg_b + 0);
        conv_mfma_k<<<270, 256, 0, stream>>>(C);
    }
    {   // L2
        ConvArgs C = mkTrunk(actA_cls, actA_reg, false, actB_cls, actB_reg, wpc[1], wpr[1],
                             cls_b + 256, reg_b + 256);
        conv_mfma_k<<<270, 256, 0, stream>>>(C);
    }
    {   // L3
        ConvArgs C = mkTrunk(actB_cls, actB_reg, false, actA_cls, actA_reg, wpc[2], wpr[2],
                             cls_b + 512, reg_b + 512);
        conv_mfma_k<<<270, 256, 0, stream>>>(C);
    }
    {   // L4
        ConvArgs C = mkTrunk(actA_cls, actA_reg, false, actB_cls, actB_reg, wpc[3], wpr[3],
                             cls_b + 768, reg_b + 768);
        conv_mfma_k<<<270, 256, 0, stream>>>(C);
    }
    {   // heads: cls 720 (3 chunks) + reg 36 (1 chunk)
        ConvArgs C;
        for (int lv = 0; lv < 5; lv++) {
            C.src0[lv] = actB_cls + (size_t)256 * pxB[lv];
            C.src1[lv] = actB_reg + (size_t)256 * pxB[lv];
        }
        C.dst0 = headout_cls; C.dst1 = headout_reg;
        C.wp0 = wpch; C.wp1 = wprh; C.bias0 = cls_hb; C.bias1 = reg_hb;
        C.Co0 = 720; C.Co1 = 36; C.CoPad0 = 768; C.CoPad1 = 64;
        C.relu = 0; C.chunks0 = 3; C.chunks1 = 1;
        conv_mfma_k<<<540, 256, 0, stream>>>(C);
    }

    // ---------- reduce + decode (all levels)
    cls_reduce_k<<<302, 256, 0, stream>>>(headout_cls, keys, cls_all);

    DecArgs D;
    {
        const float sz[5] = {32.f, 64.f, 128.f, 256.f, 512.f};
        const float ratios[3] = {0.5f, 1.0f, 2.0f};
        const float scales[3] = {1.0f, 1.25992104989487316477f, 1.58740105196819947475f};
        for (int lv = 0; lv < 5; lv++)
            for (int r = 0; r < 3; r++)
                for (int s = 0; s < 3; s++) {
                    D.aw[lv * 9 + r * 3 + s] = sz[lv] * scales[s] / sqrtf(ratios[r]);
                    D.ah[lv * 9 + r * 3 + s] = sz[lv] * scales[s] * sqrtf(ratios[r]);
                }
    }
    decode_k<<<302, 256, 0, stream>>>(headout_reg, D, boxes_all);

    // ---------- sort (descending)
    bitonic_local_full_k<<<NPAD / 4096, 1024, 0, stream>>>(keys);
    for (int size = 8192; size <= NPAD; size <<= 1) {
        for (int stride = size >> 1; stride >= 4096; stride >>= 1)
            bitonic_global_k<<<NPAD / 2 / 1024, 1024, 0, stream>>>(keys, size, stride);
        bitonic_local_k<<<NPAD / 4096, 1024, 0, stream>>>(keys, size);
    }

    // ---------- NMS + outputs
    nms_out_k<<<1, 1024, 0, stream>>>(keys, boxes_all, cls_all, out);
}

// Round 4
// 1547.471 us; speedup vs baseline: 10.8862x; 1.1620x over previous
//
#include <hip/hip_runtime.h>
#include <math.h>
#include <stdint.h>

#define NANCH 76725
#define NPAD  131072
#define NPAD2 32768
#define PXTOT 8525

typedef _Float16 half8 __attribute__((ext_vector_type(8)));
typedef float float4v __attribute__((ext_vector_type(4)));
typedef unsigned long long u64;

// activation / head buffer element sizes (floats)
#define ACT_EL   (256 * PXTOT)
#define HEADC_EL (720 * PXTOT)
#define HEADR_EL (36 * PXTOT)

// prepped weight sizes (fp16 elements): [tap9][split2][CoPad][256]
#define TRUNK_WP_EL (9 * 2 * 256 * 256)
#define CLSH_WP_EL  (9 * 2 * 768 * 256)
#define REGH_WP_EL  (9 * 2 * 64 * 256)

// ---------------------------------------------------------------- weight prep
struct PrepArgs {
    const float* src[10];
    _Float16*    dst[10];
    int Co[10], CoPad[10];
    long base[11];
};

__global__ __launch_bounds__(256) void prep_k(PrepArgs P)
{
    long idx = (long)blockIdx.x * 256 + threadIdx.x;
    if (idx >= P.base[10]) return;
    int e = 0;
    while (idx >= P.base[e + 1]) e++;
    long local = idx - P.base[e];
    int k = (int)(local & 31);
    long t2 = local >> 5;
    int Co = P.Co[e];
    int co = (int)(t2 % Co);
    int ts = (int)(t2 / Co);
    int tap = ts >> 1, s = ts & 1;
    int ci0 = k * 8;
    const float* src = P.src[e];
    half8 out;
#pragma unroll
    for (int j = 0; j < 8; j++) {
        float v = src[(size_t)(co * 256 + ci0 + j) * 9 + tap];
        _Float16 h = (_Float16)v;
        out[j] = s ? (_Float16)(v - (float)h) : h;
    }
    _Float16* dst = P.dst[e] + ((size_t)(tap * 2 + s) * P.CoPad[e] + co) * 256 + ci0;
    *(half8*)dst = out;
}

// ---------------------------------------------------------------- MFMA conv
struct ConvArgs {
    const float* src0[5];
    const float* src1[5];
    float* dst0; float* dst1;
    const _Float16* wp0; const _Float16* wp1;
    const float* bias0; const float* bias1;
    int Co0, Co1, CoPad0, CoPad1, relu, chunks0, chunks1;
};

__global__ __launch_bounds__(256, 2) void conv_mfma_k(ConvArgs A)
{
    __shared__ __align__(16) _Float16 Xs[228 * 72];

    const int cumT[5] = {100, 125, 132, 134, 135};
    const int Wt[5]   = {80, 40, 20, 10, 5};
    const int pxB[5]  = {0, 6400, 8000, 8400, 8500};

    const int gid = blockIdx.x;
    int head, chunk, t;
    if (gid < 135 * A.chunks0) { head = 0; chunk = gid / 135; t = gid % 135; }
    else { int g = gid - 135 * A.chunks0; head = 1; chunk = g / 135; t = g % 135; }

    int lv = 0;
    while (t >= cumT[lv]) lv++;
    const int tile = t - (lv ? cumT[lv - 1] : 0);
    const int W = Wt[lv], HW = W * W;
    const int pxStart = tile * 64;
    const int Ns = 2 * W + 67;

    const float* src = head ? A.src1[lv] : A.src0[lv];
    float* dst       = head ? A.dst1 : A.dst0;
    const _Float16* wp = head ? A.wp1 : A.wp0;
    const float* bias  = head ? A.bias1 : A.bias0;
    const int Co     = head ? A.Co1 : A.Co0;
    const int CoPad  = head ? A.CoPad1 : A.CoPad0;
    dst += (size_t)Co * pxB[lv];

    const int tid = threadIdx.x;
    const int lane = tid & 63;
    const int wv = tid >> 6;
    const int l15 = lane & 15;
    const int quad = lane >> 4;
    const int coW = chunk * 256 + wv * 64;
    const size_t wstride = (size_t)CoPad * 256;

    float4v acc[4][4];
#pragma unroll
    for (int i = 0; i < 4; i++)
#pragma unroll
        for (int j = 0; j < 4; j++) acc[i][j] = (float4v){0.f, 0.f, 0.f, 0.f};

    int xA[4];
#pragma unroll
    for (int mf = 0; mf < 4; mf++) {
        int px = pxStart + mf * 16 + l15;
        xA[mf] = px % W;
    }
    const half8 z8 = {(_Float16)0, (_Float16)0, (_Float16)0, (_Float16)0,
                      (_Float16)0, (_Float16)0, (_Float16)0, (_Float16)0};

    for (int ci0 = 0; ci0 < 256; ci0 += 32) {
        __syncthreads();
        {   // stage input patch (hi/lo) for this ci chunk
            const int p0 = pxStart - W - 1;
            for (int ci = wv; ci < 32; ci += 4) {
                const float* s = src + (size_t)(ci0 + ci) * HW;
                for (int sp = lane; sp < Ns; sp += 64) {
                    int p = p0 + sp;
                    float v = (p >= 0 && p < HW) ? s[p] : 0.f;
                    _Float16 h = (_Float16)v;
                    Xs[sp * 72 + ci] = h;
                    Xs[sp * 72 + 32 + ci] = (_Float16)(v - (float)h);
                }
            }
        }
        __syncthreads();

        auto loadB = [&](int tap, half8* BH, half8* BL) {
            const _Float16* wpt = wp + (size_t)(tap * 2) * wstride + ci0 + quad * 8;
#pragma unroll
            for (int nf = 0; nf < 4; nf++) {
                int co = coW + nf * 16 + l15;
                bool bok = co < CoPad;
                const _Float16* p = wpt + (size_t)co * 256;
                BH[nf] = bok ? *(const half8*)p : z8;
                BL[nf] = bok ? *(const half8*)(p + wstride) : z8;
            }
        };

        half8 BHc[4], BLc[4], BHn[4], BLn[4];
        loadB(0, BHc, BLc);

        for (int tap = 0; tap < 9; tap++) {
            const int dy = tap / 3 - 1, dx = tap % 3 - 1;
            half8 ah[4], al[4];
#pragma unroll
            for (int mf = 0; mf < 4; mf++) {
                int xx = xA[mf] + dx;
                bool val = (xx >= 0) && (xx < W);
                int row = (mf * 16 + l15) + (W + 1) + dy * W + dx;
                const _Float16* ap = &Xs[row * 72 + quad * 8];
                ah[mf] = val ? *(const half8*)ap : z8;
                al[mf] = val ? *(const half8*)(ap + 32) : z8;
            }
            if (tap < 8) loadB(tap + 1, BHn, BLn);   // prefetch next tap's B
#pragma unroll
            for (int nf = 0; nf < 4; nf++) {
#pragma unroll
                for (int mf = 0; mf < 4; mf++) {
                    acc[mf][nf] = __builtin_amdgcn_mfma_f32_16x16x32_f16(ah[mf], BHc[nf], acc[mf][nf], 0, 0, 0);
                    acc[mf][nf] = __builtin_amdgcn_mfma_f32_16x16x32_f16(ah[mf], BLc[nf], acc[mf][nf], 0, 0, 0);
                    acc[mf][nf] = __builtin_amdgcn_mfma_f32_16x16x32_f16(al[mf], BHc[nf], acc[mf][nf], 0, 0, 0);
                }
            }
            if (tap < 8) {
#pragma unroll
                for (int nf = 0; nf < 4; nf++) { BHc[nf] = BHn[nf]; BLc[nf] = BLn[nf]; }
            }
        }
    }

    // epilogue: C row = quad*4 + r, col = l15
#pragma unroll
    for (int nf = 0; nf < 4; nf++) {
        int co = coW + nf * 16 + l15;
        if (co >= Co) continue;
        float bv = bias[co];
        float* dco = dst + (size_t)co * HW;
#pragma unroll
        for (int mf = 0; mf < 4; mf++) {
            int pbase = pxStart + mf * 16 + quad * 4;
#pragma unroll
            for (int r = 0; r < 4; r++) {
                int p = pbase + r;
                if (p < HW) {
                    float v = acc[mf][nf][r] + bv;
                    if (A.relu) v = fmaxf(v, 0.f);
                    dco[p] = v;
                }
            }
        }
    }
}

// ---------------------------------------------------------------- cls reduce
// argmax MUST be in fp32 sigmoid domain: saturated classes tie at 1.0f and
// jnp.argmax picks the lowest tied class index (logit-domain argmax differs).
__global__ void cls_reduce_k(const float* __restrict__ ho,
                             u64* __restrict__ keys, int* __restrict__ cls_all)
{
    const int cumB[5] = {225, 282, 297, 301, 302};
    const int HWs[5]  = {6400, 1600, 400, 100, 25};
    const int pxB[5]  = {0, 6400, 8000, 8400, 8500};
    const int offs[5] = {0, 57600, 72000, 75600, 76500};
    int b = blockIdx.x;
    int lv = 0;
    while (b >= cumB[lv]) lv++;
    int local = (b - (lv ? cumB[lv - 1] : 0)) * 256 + threadIdx.x;
    const int HW = HWs[lv];
    if (local >= HW * 9) return;
    int a = local / HW, p = local - a * HW;
    const float* base = ho + (size_t)720 * pxB[lv] + (size_t)a * 80 * HW + p;
    float m = -1.f; int arg = 0;
    for (int c = 0; c < 80; c++) {
        float logit = base[(size_t)c * HW];
        float s = 1.0f / (1.0f + expf(-logit));
        if (s > m) { m = s; arg = c; }
    }
    float masked = (m > 0.05f) ? m : -1.0f;
    unsigned u = __float_as_uint(masked);
    unsigned su = (u & 0x80000000u) ? ~u : (u | 0x80000000u);
    int g = offs[lv] + p * 9 + a;
    keys[g] = ((u64)su << 32) | (u64)(0xFFFFFFFFu - (unsigned)g);
    cls_all[g] = arg;
}

// ---------------------------------------------------------------- decode
struct DecArgs { float aw[45]; float ah[45]; };

__global__ void decode_k(const float* __restrict__ ro, DecArgs D, float* __restrict__ boxes_all)
{
    const int cumB[5] = {225, 282, 297, 301, 302};
    const int HWs[5]  = {6400, 1600, 400, 100, 25};
    const int Wt[5]   = {80, 40, 20, 10, 5};
    const int pxB[5]  = {0, 6400, 8000, 8400, 8500};
    const int offs[5] = {0, 57600, 72000, 75600, 76500};
    const float strd[5] = {8.f, 16.f, 32.f, 64.f, 128.f};
    int b = blockIdx.x;
    int lv = 0;
    while (b >= cumB[lv]) lv++;
    int local = (b - (lv ? cumB[lv - 1] : 0)) * 256 + threadIdx.x;
    const int HW = HWs[lv], W = Wt[lv];
    if (local >= HW * 9) return;
    int a = local / HW, p = local - a * HW;
    int y = p / W, x = p - y * W;
    float cx0 = ((float)x + 0.5f) * strd[lv];
    float cy0 = ((float)y + 0.5f) * strd[lv];
    float aw = D.aw[lv * 9 + a], ahh = D.ah[lv * 9 + a];
    float ax1 = cx0 - aw * 0.5f, ax2 = cx0 + aw * 0.5f;
    float ay1 = cy0 - ahh * 0.5f, ay2 = cy0 + ahh * 0.5f;
    float w = ax2 - ax1, h = ay2 - ay1;
    float cx = ax1 + 0.5f * w, cy = ay1 + 0.5f * h;
    const float* base = ro + (size_t)36 * pxB[lv] + p;
    float l0 = base[(size_t)(a * 4 + 0) * HW];
    float l1 = base[(size_t)(a * 4 + 1) * HW];
    float l2 = base[(size_t)(a * 4 + 2) * HW];
    float l3 = base[(size_t)(a * 4 + 3) * HW];
    float dx = l0 * 0.1f, dy = l1 * 0.1f, dw = l2 * 0.2f, dh = l3 * 0.2f;
    float pcx = cx + dx * w, pcy = cy + dy * h;
    float pw = expf(dw) * w, ph = expf(dh) * h;
    float bx1 = fminf(fmaxf(pcx - 0.5f * pw, 0.f), 640.f);
    float by1 = fminf(fmaxf(pcy - 0.5f * ph, 0.f), 640.f);
    float bx2 = fminf(fmaxf(pcx + 0.5f * pw, 0.f), 640.f);
    float by2 = fminf(fmaxf(pcy + 0.5f * ph, 0.f), 640.f);
    int g = offs[lv] + p * 9 + a;
    boxes_all[g * 4 + 0] = bx1;
    boxes_all[g * 4 + 1] = by1;
    boxes_all[g * 4 + 2] = bx2;
    boxes_all[g * 4 + 3] = by2;
}

__global__ void pad_keys_k(u64* __restrict__ keys)
{
    int i = blockIdx.x * blockDim.x + threadIdx.x + NANCH;
    if (i < NPAD) keys[i] = 0ULL;
}

// ---------------------------------------------------------------- sort
// Phase 1: sort each 4096-chunk fully DESCENDING (local i direction).
__global__ __launch_bounds__(1024) void chunk_sort_desc_k(u64* __restrict__ keys)
{
    __shared__ u64 s[4096];
    const int base = blockIdx.x * 4096;
    for (int i = threadIdx.x; i < 4096; i += 1024) s[i] = keys[base + i];
    __syncthreads();
    for (int size = 2; size <= 4096; size <<= 1) {
        for (int stride = size >> 1; stride > 0; stride >>= 1) {
            for (int t = threadIdx.x; t < 2048; t += 1024) {
                int low = t & (stride - 1);
                int i = ((t - low) << 1) | low;
                int j = i + stride;
                bool desc = ((i & size) == 0);
                u64 a = s[i], b = s[j];
                if (desc ? (a < b) : (a > b)) { s[i] = b; s[j] = a; }
            }
            __syncthreads();
        }
    }
    for (int i = threadIdx.x; i < 4096; i += 1024) keys[base + i] = s[i];
}

// Phase 2: keep top-1024 of each sorted chunk (global top-1000 is a subset).
__global__ __launch_bounds__(1024) void gather_top_k(const u64* __restrict__ keys,
                                                     u64* __restrict__ keys2)
{
    int i = blockIdx.x * 1024 + threadIdx.x;          // 32768 threads
    keys2[i] = keys[(i >> 10) * 4096 + (i & 1023)];
}

__global__ void bitonic_global_k(u64* __restrict__ keys, int size, int stride)
{
    int t = blockIdx.x * blockDim.x + threadIdx.x;
    int low = t & (stride - 1);
    int i = ((t - low) << 1) | low;
    int j = i + stride;
    bool desc = ((i & size) == 0);
    u64 a = keys[i], b = keys[j];
    if (desc ? (a < b) : (a > b)) { keys[i] = b; keys[j] = a; }
}

__global__ __launch_bounds__(1024) void bitonic_local_full_k(u64* __restrict__ keys)
{
    __shared__ u64 s[4096];
    const int base = blockIdx.x * 4096;
    for (int i = threadIdx.x; i < 4096; i += 1024) s[i] = keys[base + i];
    __syncthreads();
    for (int size = 2; size <= 4096; size <<= 1) {
        for (int stride = size >> 1; stride > 0; stride >>= 1) {
            for (int t = threadIdx.x; t < 2048; t += 1024) {
                int low = t & (stride - 1);
                int i = ((t - low) << 1) | low;
                int j = i + stride;
                bool desc = (((base + i) & size) == 0);
                u64 a = s[i], b = s[j];
                if (desc ? (a < b) : (a > b)) { s[i] = b; s[j] = a; }
            }
            __syncthreads();
        }
    }
    for (int i = threadIdx.x; i < 4096; i += 1024) keys[base + i] = s[i];
}

__global__ __launch_bounds__(1024) void bitonic_local_k(u64* __restrict__ keys, int size)
{
    __shared__ u64 s[4096];
    const int base = blockIdx.x * 4096;
    for (int i = threadIdx.x; i < 4096; i += 1024) s[i] = keys[base + i];
    __syncthreads();
    const bool desc = ((base & size) == 0);
    for (int stride = 2048; stride > 0; stride >>= 1) {
        for (int t = threadIdx.x; t < 2048; t += 1024) {
            int low = t & (stride - 1);
            int i = ((t - low) << 1) | low;
            int j = i + stride;
            u64 a = s[i], b = s[j];
            if (desc ? (a < b) : (a > b)) { s[i] = b; s[j] = a; }
        }
        __syncthreads();
    }
    for (int i = threadIdx.x; i < 4096; i += 1024) keys[base + i] = s[i];
}

// ---------------------------------------------------------------- NMS (mask-based)
// cand[i*8] = {x1,y1,x2,y2,area,score,class,valid}
__global__ void gather_cand_k(const u64* __restrict__ keys,
                              const float* __restrict__ boxes_all,
                              const int* __restrict__ cls_all,
                              float* __restrict__ cand)
{
    int i = blockIdx.x * 256 + threadIdx.x;
    if (i >= 1000) return;
    u64 k = keys[i];
    unsigned shi = (unsigned)(k >> 32);
    unsigned u = (shi & 0x80000000u) ? (shi ^ 0x80000000u) : ~shi;
    float val = __uint_as_float(u);
    int anchor = (int)(0xFFFFFFFFu - (unsigned)(k & 0xFFFFFFFFull));
    float x1 = boxes_all[anchor * 4 + 0];
    float y1 = boxes_all[anchor * 4 + 1];
    float x2 = boxes_all[anchor * 4 + 2];
    float y2 = boxes_all[anchor * 4 + 3];
    cand[i * 8 + 0] = x1;
    cand[i * 8 + 1] = y1;
    cand[i * 8 + 2] = x2;
    cand[i * 8 + 3] = y2;
    cand[i * 8 + 4] = fmaxf(x2 - x1, 0.f) * fmaxf(y2 - y1, 0.f);
    cand[i * 8 + 5] = val;
    cand[i * 8 + 6] = (float)cls_all[anchor];
    cand[i * 8 + 7] = (val > 0.0f) ? 1.f : 0.f;
}

// mask[i][w] : bit j of word w set iff iou(i, j) > 0.5 and j > i
__global__ __launch_bounds__(256) void iou_mask_k(const float* __restrict__ cand,
                                                  u64* __restrict__ mask)
{
    const int i = blockIdx.x;
    const float x1 = cand[i * 8 + 0], y1 = cand[i * 8 + 1];
    const float x2 = cand[i * 8 + 2], y2 = cand[i * 8 + 3];
    const float ar = cand[i * 8 + 4];
    const int tid = threadIdx.x;
    const int wave = tid >> 6, lane = tid & 63;
    for (int base = 0; base < 1024; base += 256) {
        int j = base + tid;
        bool sup = false;
        if (j < 1000 && j > i) {
            float jx1 = cand[j * 8 + 0], jy1 = cand[j * 8 + 1];
            float jx2 = cand[j * 8 + 2], jy2 = cand[j * 8 + 3];
            float jar = cand[j * 8 + 4];
            float xx1 = fmaxf(x1, jx1), yy1 = fmaxf(y1, jy1);
            float xx2 = fminf(x2, jx2), yy2 = fminf(y2, jy2);
            float inter = fmaxf(xx2 - xx1, 0.f) * fmaxf(yy2 - yy1, 0.f);
            float iou = inter / (ar + jar - inter + 1e-8f);
            sup = iou > 0.5f;
        }
        u64 ball = __ballot(sup);
        int word = (base >> 6) + wave;
        if (lane == 0) mask[(size_t)i * 16 + word] = ball;
    }
}

// single-wave serial sweep (no barriers in loop) + output write
__global__ __launch_bounds__(256) void nms_sweep_out_k(const float* __restrict__ cand,
                                                       const u64* __restrict__ M,
                                                       float* __restrict__ out)
{
    __shared__ float C[1000 * 8];
    __shared__ int KPs[1000];
    const int tid = threadIdx.x;
    for (int i = tid; i < 8000; i += 256) C[i] = cand[i];
    __syncthreads();

    if (tid < 64) {
        const int l = tid;
        u64 s = 0;                       // lanes 0..15: suppressed-bit words
        u64 cur = M[l];                  // rows 0..3 prefetched (word l&15 of row l>>4)
        for (int base = 0; base < 1000; base += 4) {
            u64 nxt = 0;
            if (base + 8 <= 1000) nxt = M[(base + 4) * 16 + l];
#pragma unroll
            for (int k = 0; k < 4; k++) {
                int i = base + k;
                u64 sw = __shfl(s, i >> 6);
                bool alive = (C[i * 8 + 7] > 0.f) && !((sw >> (i & 63)) & 1);
                u64 rw = __shfl(cur, k * 16 + (l & 15));
                if (alive && l < 16) s |= rw;
                if (l == 0) KPs[i] = alive ? 1 : 0;
            }
            cur = nxt;
        }
    }
    __syncthreads();

    for (int i = tid; i < 1000; i += 256) {
        int kp = KPs[i];
        float m = kp ? 1.f : 0.f;
        out[i] = kp ? C[i * 8 + 5] : 0.f;
        out[1000 + i] = C[i * 8 + 6];
        out[2000 + i * 4 + 0] = m * C[i * 8 + 0];
        out[2000 + i * 4 + 1] = m * C[i * 8 + 1];
        out[2000 + i * 4 + 2] = m * C[i * 8 + 2];
        out[2000 + i * 4 + 3] = m * C[i * 8 + 3];
        out[6000 + i] = m;
    }
}

// ---------------------------------------------------------------- host
extern "C" void kernel_launch(void* const* d_in, const int* in_sizes, int n_in,
                              void* d_out, int out_size, void* d_ws, size_t ws_size,
                              hipStream_t stream)
{
    const float* feats[5];
    for (int i = 0; i < 5; i++) feats[i] = (const float*)d_in[i];
    const float* cls_w  = (const float*)d_in[5];
    const float* cls_b  = (const float*)d_in[6];
    const float* cls_hw = (const float*)d_in[7];
    const float* cls_hb = (const float*)d_in[8];
    const float* reg_w  = (const float*)d_in[9];
    const float* reg_b  = (const float*)d_in[10];
    const float* reg_hw = (const float*)d_in[11];
    const float* reg_hb = (const float*)d_in[12];
    float* out = (float*)d_out;

    // ---------- workspace layout
    char* ws = (char*)d_ws;
    size_t off = 0;
    auto alloc = [&](size_t sz) { size_t o = off; off += (sz + 255) & ~(size_t)255; return o; };

    size_t R0 = alloc((size_t)(HEADC_EL + HEADR_EL) * 4);   // headout region; overlays act-A
    float* actA_cls = (float*)(ws + R0);
    float* actA_reg = actA_cls + ACT_EL;
    float* headout_cls = (float*)(ws + R0);
    float* headout_reg = headout_cls + HEADC_EL;

    float* actB_cls = (float*)(ws + alloc((size_t)ACT_EL * 4));
    float* actB_reg = (float*)(ws + alloc((size_t)ACT_EL * 4));

    _Float16* wpc[4]; _Float16* wpr[4];
    for (int i = 0; i < 4; i++) wpc[i] = (_Float16*)(ws + alloc((size_t)TRUNK_WP_EL * 2));
    _Float16* wpch = (_Float16*)(ws + alloc((size_t)CLSH_WP_EL * 2));
    for (int i = 0; i < 4; i++) wpr[i] = (_Float16*)(ws + alloc((size_t)TRUNK_WP_EL * 2));
    _Float16* wprh = (_Float16*)(ws + alloc((size_t)REGH_WP_EL * 2));

    u64* keys  = (u64*)(ws + alloc((size_t)NPAD * 8));
    u64* keys2 = (u64*)(ws + alloc((size_t)NPAD2 * 8));
    float* boxes_all = (float*)(ws + alloc((size_t)NANCH * 16));
    int* cls_all = (int*)(ws + alloc((size_t)NANCH * 4));
    float* cand = (float*)(ws + alloc((size_t)1000 * 8 * 4));
    u64* mask = (u64*)(ws + alloc((size_t)1000 * 16 * 8));
    (void)ws_size;

    // ---------- weight prep
    PrepArgs P;
    long cum = 0;
    for (int e = 0; e < 10; e++) {
        const float* src; _Float16* dst; int Co, CoPad;
        if (e < 4)      { src = cls_w + (size_t)e * 589824; dst = wpc[e]; Co = 256; CoPad = 256; }
        else if (e == 4){ src = cls_hw;                     dst = wpch;   Co = 720; CoPad = 768; }
        else if (e < 9) { src = reg_w + (size_t)(e - 5) * 589824; dst = wpr[e - 5]; Co = 256; CoPad = 256; }
        else            { src = reg_hw;                     dst = wprh;   Co = 36;  CoPad = 64; }
        P.src[e] = src; P.dst[e] = dst; P.Co[e] = Co; P.CoPad[e] = CoPad;
        P.base[e] = cum; cum += (long)18 * Co * 32;
    }
    P.base[10] = cum;
    prep_k<<<(int)((cum + 255) / 256), 256, 0, stream>>>(P);

    pad_keys_k<<<(NPAD - NANCH + 255) / 256, 256, 0, stream>>>(keys);

    const int pxB[5] = {0, 6400, 8000, 8400, 8500};

    auto mkTrunk = [&](const float* s0base, const float* s1base, bool isFeat,
                       float* d0, float* d1, const _Float16* w0, const _Float16* w1,
                       const float* b0, const float* b1) {
        ConvArgs C;
        for (int lv = 0; lv < 5; lv++) {
            C.src0[lv] = isFeat ? feats[lv] : s0base + (size_t)256 * pxB[lv];
            C.src1[lv] = isFeat ? feats[lv] : s1base + (size_t)256 * pxB[lv];
        }
        C.dst0 = d0; C.dst1 = d1; C.wp0 = w0; C.wp1 = w1; C.bias0 = b0; C.bias1 = b1;
        C.Co0 = 256; C.Co1 = 256; C.CoPad0 = 256; C.CoPad1 = 256;
        C.relu = 1; C.chunks0 = 1; C.chunks1 = 1;
        return C;
    };

    {   ConvArgs C = mkTrunk(nullptr, nullptr, true, actA_cls, actA_reg, wpc[0], wpr[0],
                             cls_b + 0, reg_b + 0);
        conv_mfma_k<<<270, 256, 0, stream>>>(C); }
    {   ConvArgs C = mkTrunk(actA_cls, actA_reg, false, actB_cls, actB_reg, wpc[1], wpr[1],
                             cls_b + 256, reg_b + 256);
        conv_mfma_k<<<270, 256, 0, stream>>>(C); }
    {   ConvArgs C = mkTrunk(actB_cls, actB_reg, false, actA_cls, actA_reg, wpc[2], wpr[2],
                             cls_b + 512, reg_b + 512);
        conv_mfma_k<<<270, 256, 0, stream>>>(C); }
    {   ConvArgs C = mkTrunk(actA_cls, actA_reg, false, actB_cls, actB_reg, wpc[3], wpr[3],
                             cls_b + 768, reg_b + 768);
        conv_mfma_k<<<270, 256, 0, stream>>>(C); }
    {   // heads: cls 720 (3 chunks) + reg 36 (1 chunk)
        ConvArgs C;
        for (int lv = 0; lv < 5; lv++) {
            C.src0[lv] = actB_cls + (size_t)256 * pxB[lv];
            C.src1[lv] = actB_reg + (size_t)256 * pxB[lv];
        }
        C.dst0 = headout_cls; C.dst1 = headout_reg;
        C.wp0 = wpch; C.wp1 = wprh; C.bias0 = cls_hb; C.bias1 = reg_hb;
        C.Co0 = 720; C.Co1 = 36; C.CoPad0 = 768; C.CoPad1 = 64;
        C.relu = 0; C.chunks0 = 3; C.chunks1 = 1;
        conv_mfma_k<<<540, 256, 0, stream>>>(C);
    }

    // ---------- reduce + decode
    cls_reduce_k<<<302, 256, 0, stream>>>(headout_cls, keys, cls_all);

    DecArgs D;
    {
        const float sz[5] = {32.f, 64.f, 128.f, 256.f, 512.f};
        const float ratios[3] = {0.5f, 1.0f, 2.0f};
        const float scales[3] = {1.0f, 1.25992104989487316477f, 1.58740105196819947475f};
        for (int lv = 0; lv < 5; lv++)
            for (int r = 0; r < 3; r++)
                for (int s = 0; s < 3; s++) {
                    D.aw[lv * 9 + r * 3 + s] = sz[lv] * scales[s] / sqrtf(ratios[r]);
                    D.ah[lv * 9 + r * 3 + s] = sz[lv] * scales[s] * sqrtf(ratios[r]);
                }
    }
    decode_k<<<302, 256, 0, stream>>>(headout_reg, D, boxes_all);

    // ---------- top-K sort: chunk-sort -> keep top-1024/chunk -> sort 32768
    chunk_sort_desc_k<<<NPAD / 4096, 1024, 0, stream>>>(keys);
    gather_top_k<<<NPAD2 / 1024, 1024, 0, stream>>>(keys, keys2);
    bitonic_local_full_k<<<NPAD2 / 4096, 1024, 0, stream>>>(keys2);
    for (int size = 8192; size <= NPAD2; size <<= 1) {
        for (int stride = size >> 1; stride >= 4096; stride >>= 1)
            bitonic_global_k<<<NPAD2 / 2 / 1024, 1024, 0, stream>>>(keys2, size, stride);
        bitonic_local_k<<<NPAD2 / 4096, 1024, 0, stream>>>(keys2, size);
    }

    // ---------- NMS: gather -> IoU mask -> single-wave sweep + output
    gather_cand_k<<<4, 256, 0, stream>>>(keys2, boxes_all, cls_all, cand);
    iou_mask_k<<<1000, 256, 0, stream>>>(cand, mask);
    nms_sweep_out_k<<<1, 256, 0, stream>>>(cand, mask, out);
}

// Round 5
// 1385.135 us; speedup vs baseline: 12.1621x; 1.1172x over previous
//
#include <hip/hip_runtime.h>
#include <math.h>
#include <stdint.h>

#define NANCH 76725
#define NPAD  131072
#define NPAD2 32768
#define PXTOT 8525

typedef _Float16 half8 __attribute__((ext_vector_type(8)));
typedef _Float16 half4 __attribute__((ext_vector_type(4)));
typedef float float4v __attribute__((ext_vector_type(4)));
typedef unsigned long long u64;

#define ACT2_EL  ((size_t)PXTOT * 512)     // [px][hi256|lo256] fp16
#define HEADC_EL (720 * PXTOT)
#define HEADR_EL (36 * PXTOT)

// prepped weight sizes (fp16 elements): [tap9][split2][CoPad][256]
#define TRUNK_WP_EL (9 * 2 * 256 * 256)
#define CLSH_WP_EL  (9 * 2 * 768 * 256)
#define REGH_WP_EL  (9 * 2 * 64 * 256)

// ---------------------------------------------------------------- weight prep
struct PrepArgs {
    const float* src[10];
    _Float16*    dst[10];
    int Co[10], CoPad[10];
    long base[11];
};

__global__ __launch_bounds__(256) void prep_k(PrepArgs P)
{
    long idx = (long)blockIdx.x * 256 + threadIdx.x;
    if (idx >= P.base[10]) return;
    int e = 0;
    while (idx >= P.base[e + 1]) e++;
    long local = idx - P.base[e];
    int k = (int)(local & 31);
    long t2 = local >> 5;
    int Co = P.Co[e];
    int co = (int)(t2 % Co);
    int ts = (int)(t2 / Co);
    int tap = ts >> 1, s = ts & 1;
    int ci0 = k * 8;
    const float* src = P.src[e];
    half8 out;
#pragma unroll
    for (int j = 0; j < 8; j++) {
        float v = src[(size_t)(co * 256 + ci0 + j) * 9 + tap];
        _Float16 h = (_Float16)v;
        out[j] = s ? (_Float16)(v - (float)h) : h;
    }
    _Float16* dst = P.dst[e] + ((size_t)(tap * 2 + s) * P.CoPad[e] + co) * 256 + ci0;
    *(half8*)dst = out;
}

// ---------------------------------------------------------------- feats repack
// feats fp32 [256][HW] -> act2 [px][hi256|lo256] fp16
struct RepArgs { const float* src[5]; _Float16* dst; };

__global__ __launch_bounds__(256) void repack_k(RepArgs R)
{
    __shared__ float T[64][257];
    const int cumT[5] = {100, 125, 132, 134, 135};
    const int Wt[5]   = {80, 40, 20, 10, 5};
    const int pxB[5]  = {0, 6400, 8000, 8400, 8500};
    int t = blockIdx.x;
    int lv = 0; while (t >= cumT[lv]) lv++;
    int tile = t - (lv ? cumT[lv - 1] : 0);
    const int HW = Wt[lv] * Wt[lv];
    const int pxStart = tile * 64;
    const float* src = R.src[lv];
    const int tid = threadIdx.x, w = tid >> 6, l6 = tid & 63;
    int p = pxStart + l6;
    bool ok = p < HW;
    for (int ci = w; ci < 256; ci += 4)
        T[l6][ci] = ok ? src[(size_t)ci * HW + p] : 0.f;
    __syncthreads();
    _Float16* dst = R.dst + (size_t)pxB[lv] * 512;
    for (int px = w; px < 64; px += 4) {
        int pp = pxStart + px;
        if (pp >= HW) continue;
        half4 h, l;
#pragma unroll
        for (int j = 0; j < 4; j++) {
            float v = T[px][l6 * 4 + j];
            _Float16 hh = (_Float16)v;
            h[j] = hh; l[j] = (_Float16)(v - (float)hh);
        }
        *(half4*)(dst + (size_t)pp * 512 + l6 * 4) = h;
        *(half4*)(dst + (size_t)pp * 512 + 256 + l6 * 4) = l;
    }
}

// ---------------------------------------------------------------- conv (1-wave blocks, no LDS)
// wave = 64 px x 64 co. A from act2 [px][hi|lo], B from prepped weights.
struct C2Args {
    const _Float16* aIn0; const _Float16* aIn1;
    _Float16* aOut0; _Float16* aOut1;     // trunk mode (mode=0)
    float* hOut0; float* hOut1;           // head mode  (mode=1), layout [co][px]
    const _Float16* wp0; const _Float16* wp1;
    const float* bias0; const float* bias1;
    int chunks0, chunks1, CoPad0, CoPad1, Co0, Co1, mode;
};

__global__ __launch_bounds__(64) void conv2_k(C2Args A)
{
    const int cumT[5] = {100, 125, 132, 134, 135};
    const int Wt[5]   = {80, 40, 20, 10, 5};
    const int pxB[5]  = {0, 6400, 8000, 8400, 8500};

    int gid = blockIdx.x;
    int head, local;
    if (gid < 135 * A.chunks0) { head = 0; local = gid; }
    else { head = 1; local = gid - 135 * A.chunks0; }
    int chunk = local / 135, t = local - chunk * 135;
    int lv = 0; while (t >= cumT[lv]) lv++;
    int tile = t - (lv ? cumT[lv - 1] : 0);
    const int W = Wt[lv], HW = W * W, pxStart = tile * 64;

    const _Float16* aIn = (head ? A.aIn1 : A.aIn0) + (size_t)pxB[lv] * 512;
    const _Float16* wp  = head ? A.wp1 : A.wp0;
    const float* bias   = head ? A.bias1 : A.bias0;
    const int CoPad     = head ? A.CoPad1 : A.CoPad0;
    const int Co        = head ? A.Co1 : A.Co0;
    const size_t wstride = (size_t)CoPad * 256;

    const int lane = threadIdx.x;
    const int l15 = lane & 15;
    const int quad = lane >> 4;
    const int coW = chunk * 64;

    int coN[4];
#pragma unroll
    for (int nf = 0; nf < 4; nf++) coN[nf] = coW + nf * 16 + l15;

    int pxA[4], xA[4];
#pragma unroll
    for (int mf = 0; mf < 4; mf++) {
        pxA[mf] = pxStart + mf * 16 + l15;
        xA[mf] = pxA[mf] % W;
    }

    float4v acc[4][4];
#pragma unroll
    for (int i = 0; i < 4; i++)
#pragma unroll
        for (int j = 0; j < 4; j++) acc[i][j] = (float4v){0.f, 0.f, 0.f, 0.f};

    const half8 z8 = {(_Float16)0, (_Float16)0, (_Float16)0, (_Float16)0,
                      (_Float16)0, (_Float16)0, (_Float16)0, (_Float16)0};

    for (int tap = 0; tap < 9; tap++) {
        const int dy = tap / 3 - 1, dx = tap % 3 - 1;
        int aoff[4]; bool av[4];
#pragma unroll
        for (int mf = 0; mf < 4; mf++) {
            int xx = xA[mf] + dx;
            int pp = pxA[mf] + dy * W + dx;
            av[mf] = (pxA[mf] < HW) && (xx >= 0) && (xx < W) && (pp >= 0) && (pp < HW);
            int ppc = min(max(pp, 0), HW - 1);
            aoff[mf] = ppc * 512 + quad * 8;
        }
        const _Float16* bh_base = wp + (size_t)(2 * tap) * wstride + quad * 8;
        const _Float16* bl_base = bh_base + wstride;
        int boff[4];
#pragma unroll
        for (int nf = 0; nf < 4; nf++) boff[nf] = coN[nf] * 256;

#pragma unroll
        for (int s = 0; s < 8; s++) {
            half8 ah[4], al[4], bh[4], bl[4];
#pragma unroll
            for (int mf = 0; mf < 4; mf++) {
                const _Float16* p = aIn + (aoff[mf] + s * 32);
                ah[mf] = av[mf] ? *(const half8*)p : z8;
                al[mf] = av[mf] ? *(const half8*)(p + 256) : z8;
            }
#pragma unroll
            for (int nf = 0; nf < 4; nf++) {
                bh[nf] = *(const half8*)(bh_base + boff[nf] + s * 32);
                bl[nf] = *(const half8*)(bl_base + boff[nf] + s * 32);
            }
#pragma unroll
            for (int nf = 0; nf < 4; nf++) {
#pragma unroll
                for (int mf = 0; mf < 4; mf++) {
                    acc[mf][nf] = __builtin_amdgcn_mfma_f32_16x16x32_f16(ah[mf], bh[nf], acc[mf][nf], 0, 0, 0);
                    acc[mf][nf] = __builtin_amdgcn_mfma_f32_16x16x32_f16(ah[mf], bl[nf], acc[mf][nf], 0, 0, 0);
                    acc[mf][nf] = __builtin_amdgcn_mfma_f32_16x16x32_f16(al[mf], bh[nf], acc[mf][nf], 0, 0, 0);
                }
            }
        }
    }

    float bv[4];
#pragma unroll
    for (int nf = 0; nf < 4; nf++) bv[nf] = bias[coN[nf]];

    if (A.mode == 0) {
        _Float16* ao = (head ? A.aOut1 : A.aOut0) + (size_t)pxB[lv] * 512;
#pragma unroll
        for (int nf = 0; nf < 4; nf++) {
#pragma unroll
            for (int mf = 0; mf < 4; mf++) {
#pragma unroll
                for (int r = 0; r < 4; r++) {
                    int px = pxStart + mf * 16 + quad * 4 + r;
                    if (px < HW) {
                        float v = fmaxf(acc[mf][nf][r] + bv[nf], 0.f);
                        _Float16 h = (_Float16)v;
                        _Float16 lo = (_Float16)(v - (float)h);
                        ao[(size_t)px * 512 + coN[nf]] = h;
                        ao[(size_t)px * 512 + 256 + coN[nf]] = lo;
                    }
                }
            }
        }
    } else {
        float* ho = (head ? A.hOut1 : A.hOut0) + (size_t)Co * pxB[lv];
#pragma unroll
        for (int nf = 0; nf < 4; nf++) {
            if (coN[nf] < Co) {
                float* col = ho + (size_t)coN[nf] * HW;
#pragma unroll
                for (int mf = 0; mf < 4; mf++) {
#pragma unroll
                    for (int r = 0; r < 4; r++) {
                        int px = pxStart + mf * 16 + quad * 4 + r;
                        if (px < HW) col[px] = acc[mf][nf][r] + bv[nf];
                    }
                }
            }
        }
    }
}

// ---------------------------------------------------------------- cls reduce
// argmax MUST be in fp32 sigmoid domain: saturated classes tie at 1.0f and
// jnp.argmax picks the lowest tied class index (logit-domain argmax differs).
__global__ void cls_reduce_k(const float* __restrict__ ho,
                             u64* __restrict__ keys, int* __restrict__ cls_all)
{
    const int cumB[5] = {225, 282, 297, 301, 302};
    const int HWs[5]  = {6400, 1600, 400, 100, 25};
    const int pxB[5]  = {0, 6400, 8000, 8400, 8500};
    const int offs[5] = {0, 57600, 72000, 75600, 76500};
    int b = blockIdx.x;
    int lv = 0;
    while (b >= cumB[lv]) lv++;
    int local = (b - (lv ? cumB[lv - 1] : 0)) * 256 + threadIdx.x;
    const int HW = HWs[lv];
    if (local >= HW * 9) return;
    int a = local / HW, p = local - a * HW;
    const float* base = ho + (size_t)720 * pxB[lv] + (size_t)a * 80 * HW + p;
    float m = -1.f; int arg = 0;
    for (int c = 0; c < 80; c++) {
        float logit = base[(size_t)c * HW];
        float s = 1.0f / (1.0f + expf(-logit));
        if (s > m) { m = s; arg = c; }
    }
    float masked = (m > 0.05f) ? m : -1.0f;
    unsigned u = __float_as_uint(masked);
    unsigned su = (u & 0x80000000u) ? ~u : (u | 0x80000000u);
    int g = offs[lv] + p * 9 + a;
    keys[g] = ((u64)su << 32) | (u64)(0xFFFFFFFFu - (unsigned)g);
    cls_all[g] = arg;
}

// ---------------------------------------------------------------- decode
struct DecArgs { float aw[45]; float ah[45]; };

__global__ void decode_k(const float* __restrict__ ro, DecArgs D, float* __restrict__ boxes_all)
{
    const int cumB[5] = {225, 282, 297, 301, 302};
    const int HWs[5]  = {6400, 1600, 400, 100, 25};
    const int Wt[5]   = {80, 40, 20, 10, 5};
    const int pxB[5]  = {0, 6400, 8000, 8400, 8500};
    const int offs[5] = {0, 57600, 72000, 75600, 76500};
    const float strd[5] = {8.f, 16.f, 32.f, 64.f, 128.f};
    int b = blockIdx.x;
    int lv = 0;
    while (b >= cumB[lv]) lv++;
    int local = (b - (lv ? cumB[lv - 1] : 0)) * 256 + threadIdx.x;
    const int HW = HWs[lv], W = Wt[lv];
    if (local >= HW * 9) return;
    int a = local / HW, p = local - a * HW;
    int y = p / W, x = p - y * W;
    float cx0 = ((float)x + 0.5f) * strd[lv];
    float cy0 = ((float)y + 0.5f) * strd[lv];
    float aw = D.aw[lv * 9 + a], ahh = D.ah[lv * 9 + a];
    float ax1 = cx0 - aw * 0.5f, ax2 = cx0 + aw * 0.5f;
    float ay1 = cy0 - ahh * 0.5f, ay2 = cy0 + ahh * 0.5f;
    float w = ax2 - ax1, h = ay2 - ay1;
    float cx = ax1 + 0.5f * w, cy = ay1 + 0.5f * h;
    const float* base = ro + (size_t)36 * pxB[lv] + p;
    float l0 = base[(size_t)(a * 4 + 0) * HW];
    float l1 = base[(size_t)(a * 4 + 1) * HW];
    float l2 = base[(size_t)(a * 4 + 2) * HW];
    float l3 = base[(size_t)(a * 4 + 3) * HW];
    float dx = l0 * 0.1f, dy = l1 * 0.1f, dw = l2 * 0.2f, dh = l3 * 0.2f;
    float pcx = cx + dx * w, pcy = cy + dy * h;
    float pw = expf(dw) * w, ph = expf(dh) * h;
    float bx1 = fminf(fmaxf(pcx - 0.5f * pw, 0.f), 640.f);
    float by1 = fminf(fmaxf(pcy - 0.5f * ph, 0.f), 640.f);
    float bx2 = fminf(fmaxf(pcx + 0.5f * pw, 0.f), 640.f);
    float by2 = fminf(fmaxf(pcy + 0.5f * ph, 0.f), 640.f);
    int g = offs[lv] + p * 9 + a;
    boxes_all[g * 4 + 0] = bx1;
    boxes_all[g * 4 + 1] = by1;
    boxes_all[g * 4 + 2] = bx2;
    boxes_all[g * 4 + 3] = by2;
}

__global__ void pad_keys_k(u64* __restrict__ keys)
{
    int i = blockIdx.x * blockDim.x + threadIdx.x + NANCH;
    if (i < NPAD) keys[i] = 0ULL;
}

// ---------------------------------------------------------------- sort
__global__ __launch_bounds__(1024) void chunk_sort_desc_k(u64* __restrict__ keys)
{
    __shared__ u64 s[4096];
    const int base = blockIdx.x * 4096;
    for (int i = threadIdx.x; i < 4096; i += 1024) s[i] = keys[base + i];
    __syncthreads();
    for (int size = 2; size <= 4096; size <<= 1) {
        for (int stride = size >> 1; stride > 0; stride >>= 1) {
            for (int t = threadIdx.x; t < 2048; t += 1024) {
                int low = t & (stride - 1);
                int i = ((t - low) << 1) | low;
                int j = i + stride;
                bool desc = ((i & size) == 0);
                u64 a = s[i], b = s[j];
                if (desc ? (a < b) : (a > b)) { s[i] = b; s[j] = a; }
            }
            __syncthreads();
        }
    }
    for (int i = threadIdx.x; i < 4096; i += 1024) keys[base + i] = s[i];
}

__global__ __launch_bounds__(1024) void gather_top_k(const u64* __restrict__ keys,
                                                     u64* __restrict__ keys2)
{
    int i = blockIdx.x * 1024 + threadIdx.x;
    keys2[i] = keys[(i >> 10) * 4096 + (i & 1023)];
}

__global__ void bitonic_global_k(u64* __restrict__ keys, int size, int stride)
{
    int t = blockIdx.x * blockDim.x + threadIdx.x;
    int low = t & (stride - 1);
    int i = ((t - low) << 1) | low;
    int j = i + stride;
    bool desc = ((i & size) == 0);
    u64 a = keys[i], b = keys[j];
    if (desc ? (a < b) : (a > b)) { keys[i] = b; keys[j] = a; }
}

__global__ __launch_bounds__(1024) void bitonic_local_full_k(u64* __restrict__ keys)
{
    __shared__ u64 s[4096];
    const int base = blockIdx.x * 4096;
    for (int i = threadIdx.x; i < 4096; i += 1024) s[i] = keys[base + i];
    __syncthreads();
    for (int size = 2; size <= 4096; size <<= 1) {
        for (int stride = size >> 1; stride > 0; stride >>= 1) {
            for (int t = threadIdx.x; t < 2048; t += 1024) {
                int low = t & (stride - 1);
                int i = ((t - low) << 1) | low;
                int j = i + stride;
                bool desc = (((base + i) & size) == 0);
                u64 a = s[i], b = s[j];
                if (desc ? (a < b) : (a > b)) { s[i] = b; s[j] = a; }
            }
            __syncthreads();
        }
    }
    for (int i = threadIdx.x; i < 4096; i += 1024) keys[base + i] = s[i];
}

__global__ __launch_bounds__(1024) void bitonic_local_k(u64* __restrict__ keys, int size)
{
    __shared__ u64 s[4096];
    const int base = blockIdx.x * 4096;
    for (int i = threadIdx.x; i < 4096; i += 1024) s[i] = keys[base + i];
    __syncthreads();
    const bool desc = ((base & size) == 0);
    for (int stride = 2048; stride > 0; stride >>= 1) {
        for (int t = threadIdx.x; t < 2048; t += 1024) {
            int low = t & (stride - 1);
            int i = ((t - low) << 1) | low;
            int j = i + stride;
            u64 a = s[i], b = s[j];
            if (desc ? (a < b) : (a > b)) { s[i] = b; s[j] = a; }
        }
        __syncthreads();
    }
    for (int i = threadIdx.x; i < 4096; i += 1024) keys[base + i] = s[i];
}

// ---------------------------------------------------------------- NMS (mask-based)
__global__ void gather_cand_k(const u64* __restrict__ keys,
                              const float* __restrict__ boxes_all,
                              const int* __restrict__ cls_all,
                              float* __restrict__ cand)
{
    int i = blockIdx.x * 256 + threadIdx.x;
    if (i >= 1000) return;
    u64 k = keys[i];
    unsigned shi = (unsigned)(k >> 32);
    unsigned u = (shi & 0x80000000u) ? (shi ^ 0x80000000u) : ~shi;
    float val = __uint_as_float(u);
    int anchor = (int)(0xFFFFFFFFu - (unsigned)(k & 0xFFFFFFFFull));
    float x1 = boxes_all[anchor * 4 + 0];
    float y1 = boxes_all[anchor * 4 + 1];
    float x2 = boxes_all[anchor * 4 + 2];
    float y2 = boxes_all[anchor * 4 + 3];
    cand[i * 8 + 0] = x1;
    cand[i * 8 + 1] = y1;
    cand[i * 8 + 2] = x2;
    cand[i * 8 + 3] = y2;
    cand[i * 8 + 4] = fmaxf(x2 - x1, 0.f) * fmaxf(y2 - y1, 0.f);
    cand[i * 8 + 5] = val;
    cand[i * 8 + 6] = (float)cls_all[anchor];
    cand[i * 8 + 7] = (val > 0.0f) ? 1.f : 0.f;
}

__global__ __launch_bounds__(256) void iou_mask_k(const float* __restrict__ cand,
                                                  u64* __restrict__ mask)
{
    const int i = blockIdx.x;
    const float x1 = cand[i * 8 + 0], y1 = cand[i * 8 + 1];
    const float x2 = cand[i * 8 + 2], y2 = cand[i * 8 + 3];
    const float ar = cand[i * 8 + 4];
    const int tid = threadIdx.x;
    const int wave = tid >> 6, lane = tid & 63;
    for (int base = 0; base < 1024; base += 256) {
        int j = base + tid;
        bool sup = false;
        if (j < 1000 && j > i) {
            float jx1 = cand[j * 8 + 0], jy1 = cand[j * 8 + 1];
            float jx2 = cand[j * 8 + 2], jy2 = cand[j * 8 + 3];
            float jar = cand[j * 8 + 4];
            float xx1 = fmaxf(x1, jx1), yy1 = fmaxf(y1, jy1);
            float xx2 = fminf(x2, jx2), yy2 = fminf(y2, jy2);
            float inter = fmaxf(xx2 - xx1, 0.f) * fmaxf(yy2 - yy1, 0.f);
            float iou = inter / (ar + jar - inter + 1e-8f);
            sup = iou > 0.5f;
        }
        u64 ball = __ballot(sup);
        int word = (base >> 6) + wave;
        if (lane == 0) mask[(size_t)i * 16 + word] = ball;
    }
}

__global__ __launch_bounds__(256) void nms_sweep_out_k(const float* __restrict__ cand,
                                                       const u64* __restrict__ M,
                                                       float* __restrict__ out)
{
    __shared__ float C[1000 * 8];
    __shared__ int KPs[1000];
    const int tid = threadIdx.x;
    for (int i = tid; i < 8000; i += 256) C[i] = cand[i];
    __syncthreads();

    if (tid < 64) {
        const int l = tid;
        u64 s = 0;
        u64 cur = M[l];
        for (int base = 0; base < 1000; base += 4) {
            u64 nxt = 0;
            if (base + 8 <= 1000) nxt = M[(base + 4) * 16 + l];
#pragma unroll
            for (int k = 0; k < 4; k++) {
                int i = base + k;
                u64 sw = __shfl(s, i >> 6);
                bool alive = (C[i * 8 + 7] > 0.f) && !((sw >> (i & 63)) & 1);
                u64 rw = __shfl(cur, k * 16 + (l & 15));
                if (alive && l < 16) s |= rw;
                if (l == 0) KPs[i] = alive ? 1 : 0;
            }
            cur = nxt;
        }
    }
    __syncthreads();

    for (int i = tid; i < 1000; i += 256) {
        int kp = KPs[i];
        float m = kp ? 1.f : 0.f;
        out[i] = kp ? C[i * 8 + 5] : 0.f;
        out[1000 + i] = C[i * 8 + 6];
        out[2000 + i * 4 + 0] = m * C[i * 8 + 0];
        out[2000 + i * 4 + 1] = m * C[i * 8 + 1];
        out[2000 + i * 4 + 2] = m * C[i * 8 + 2];
        out[2000 + i * 4 + 3] = m * C[i * 8 + 3];
        out[6000 + i] = m;
    }
}

// ---------------------------------------------------------------- host
extern "C" void kernel_launch(void* const* d_in, const int* in_sizes, int n_in,
                              void* d_out, int out_size, void* d_ws, size_t ws_size,
                              hipStream_t stream)
{
    const float* feats[5];
    for (int i = 0; i < 5; i++) feats[i] = (const float*)d_in[i];
    const float* cls_w  = (const float*)d_in[5];
    const float* cls_b  = (const float*)d_in[6];
    const float* cls_hw = (const float*)d_in[7];
    const float* cls_hb = (const float*)d_in[8];
    const float* reg_w  = (const float*)d_in[9];
    const float* reg_b  = (const float*)d_in[10];
    const float* reg_hw = (const float*)d_in[11];
    const float* reg_hb = (const float*)d_in[12];
    float* out = (float*)d_out;

    // ---------- workspace layout
    char* ws = (char*)d_ws;
    size_t off = 0;
    auto alloc = [&](size_t sz) { size_t o = off; off += (sz + 255) & ~(size_t)255; return o; };

    // region0: act2_feats (early) overlaid by headout (late; head conv runs after L1)
    size_t R0 = alloc((size_t)(HEADC_EL + HEADR_EL) * 4);
    _Float16* act2_feats = (_Float16*)(ws + R0);
    float* headout_cls = (float*)(ws + R0);
    float* headout_reg = headout_cls + HEADC_EL;

    _Float16* a2_clsA = (_Float16*)(ws + alloc(ACT2_EL * 2));
    _Float16* a2_regA = (_Float16*)(ws + alloc(ACT2_EL * 2));
    _Float16* a2_clsB = (_Float16*)(ws + alloc(ACT2_EL * 2));
    _Float16* a2_regB = (_Float16*)(ws + alloc(ACT2_EL * 2));

    _Float16* wpc[4]; _Float16* wpr[4];
    for (int i = 0; i < 4; i++) wpc[i] = (_Float16*)(ws + alloc((size_t)TRUNK_WP_EL * 2));
    _Float16* wpch = (_Float16*)(ws + alloc((size_t)CLSH_WP_EL * 2));
    for (int i = 0; i < 4; i++) wpr[i] = (_Float16*)(ws + alloc((size_t)TRUNK_WP_EL * 2));
    _Float16* wprh = (_Float16*)(ws + alloc((size_t)REGH_WP_EL * 2));

    u64* keys  = (u64*)(ws + alloc((size_t)NPAD * 8));
    u64* keys2 = (u64*)(ws + alloc((size_t)NPAD2 * 8));
    float* boxes_all = (float*)(ws + alloc((size_t)NANCH * 16));
    int* cls_all = (int*)(ws + alloc((size_t)NANCH * 4));
    float* cand = (float*)(ws + alloc((size_t)1000 * 8 * 4));
    u64* mask = (u64*)(ws + alloc((size_t)1000 * 16 * 8));
    (void)ws_size;

    // ---------- weight prep
    PrepArgs P;
    long cum = 0;
    for (int e = 0; e < 10; e++) {
        const float* src; _Float16* dst; int Co, CoPad;
        if (e < 4)      { src = cls_w + (size_t)e * 589824; dst = wpc[e]; Co = 256; CoPad = 256; }
        else if (e == 4){ src = cls_hw;                     dst = wpch;   Co = 720; CoPad = 768; }
        else if (e < 9) { src = reg_w + (size_t)(e - 5) * 589824; dst = wpr[e - 5]; Co = 256; CoPad = 256; }
        else            { src = reg_hw;                     dst = wprh;   Co = 36;  CoPad = 64; }
        P.src[e] = src; P.dst[e] = dst; P.Co[e] = Co; P.CoPad[e] = CoPad;
        P.base[e] = cum; cum += (long)18 * Co * 32;
    }
    P.base[10] = cum;
    prep_k<<<(int)((cum + 255) / 256), 256, 0, stream>>>(P);

    pad_keys_k<<<(NPAD - NANCH + 255) / 256, 256, 0, stream>>>(keys);

    // ---------- feats repack
    RepArgs R;
    for (int lv = 0; lv < 5; lv++) R.src[lv] = feats[lv];
    R.dst = act2_feats;
    repack_k<<<135, 256, 0, stream>>>(R);

    // ---------- conv layers
    auto trunk = [&](const _Float16* i0, const _Float16* i1, _Float16* o0, _Float16* o1,
                     const _Float16* w0, const _Float16* w1, const float* b0, const float* b1) {
        C2Args C;
        C.aIn0 = i0; C.aIn1 = i1; C.aOut0 = o0; C.aOut1 = o1;
        C.hOut0 = nullptr; C.hOut1 = nullptr;
        C.wp0 = w0; C.wp1 = w1; C.bias0 = b0; C.bias1 = b1;
        C.chunks0 = 4; C.chunks1 = 4; C.CoPad0 = 256; C.CoPad1 = 256;
        C.Co0 = 256; C.Co1 = 256; C.mode = 0;
        conv2_k<<<1080, 64, 0, stream>>>(C);
    };
    trunk(act2_feats, act2_feats, a2_clsA, a2_regA, wpc[0], wpr[0], cls_b + 0,   reg_b + 0);
    trunk(a2_clsA,    a2_regA,    a2_clsB, a2_regB, wpc[1], wpr[1], cls_b + 256, reg_b + 256);
    trunk(a2_clsB,    a2_regB,    a2_clsA, a2_regA, wpc[2], wpr[2], cls_b + 512, reg_b + 512);
    trunk(a2_clsA,    a2_regA,    a2_clsB, a2_regB, wpc[3], wpr[3], cls_b + 768, reg_b + 768);

    {   // head convs: cls 720 (12 chunks) + reg 36 (1 chunk)
        C2Args C;
        C.aIn0 = a2_clsB; C.aIn1 = a2_regB;
        C.aOut0 = nullptr; C.aOut1 = nullptr;
        C.hOut0 = headout_cls; C.hOut1 = headout_reg;
        C.wp0 = wpch; C.wp1 = wprh; C.bias0 = cls_hb; C.bias1 = reg_hb;
        C.chunks0 = 12; C.chunks1 = 1; C.CoPad0 = 768; C.CoPad1 = 64;
        C.Co0 = 720; C.Co1 = 36; C.mode = 1;
        conv2_k<<<135 * 13, 64, 0, stream>>>(C);
    }

    // ---------- reduce + decode
    cls_reduce_k<<<302, 256, 0, stream>>>(headout_cls, keys, cls_all);

    DecArgs D;
    {
        const float sz[5] = {32.f, 64.f, 128.f, 256.f, 512.f};
        const float ratios[3] = {0.5f, 1.0f, 2.0f};
        const float scales[3] = {1.0f, 1.25992104989487316477f, 1.58740105196819947475f};
        for (int lv = 0; lv < 5; lv++)
            for (int r = 0; r < 3; r++)
                for (int s = 0; s < 3; s++) {
                    D.aw[lv * 9 + r * 3 + s] = sz[lv] * scales[s] / sqrtf(ratios[r]);
                    D.ah[lv * 9 + r * 3 + s] = sz[lv] * scales[s] * sqrtf(ratios[r]);
                }
    }
    decode_k<<<302, 256, 0, stream>>>(headout_reg, D, boxes_all);

    // ---------- top-K sort
    chunk_sort_desc_k<<<NPAD / 4096, 1024, 0, stream>>>(keys);
    gather_top_k<<<NPAD2 / 1024, 1024, 0, stream>>>(keys, keys2);
    bitonic_local_full_k<<<NPAD2 / 4096, 1024, 0, stream>>>(keys2);
    for (int size = 8192; size <= NPAD2; size <<= 1) {
        for (int stride = size >> 1; stride >= 4096; stride >>= 1)
            bitonic_global_k<<<NPAD2 / 2 / 1024, 1024, 0, stream>>>(keys2, size, stride);
        bitonic_local_k<<<NPAD2 / 4096, 1024, 0, stream>>>(keys2, size);
    }

    // ---------- NMS
    gather_cand_k<<<4, 256, 0, stream>>>(keys2, boxes_all, cls_all, cand);
    iou_mask_k<<<1000, 256, 0, stream>>>(cand, mask);
    nms_sweep_out_k<<<1, 256, 0, stream>>>(cand, mask, out);
}